// Round 12
// baseline (764.921 us; speedup 1.0000x reference)
//
#include <hip/hip_runtime.h>
#include <math.h>

typedef unsigned short u16;
typedef __attribute__((ext_vector_type(8))) short bf16x8;
typedef __attribute__((ext_vector_type(4))) float f32x4;

#define BSZ 4
#define TLEN 2048
#define DDIM 1024
#define NH 16
#define HDIM 64
#define NKOPS 4
#define RDIM 48
#define HR 768     // NH*RDIM
#define HHD 1024   // NH*HDIM
#define LNEPS 1e-5f
#define GSPLIT 4
#define GCHUNK 512
#define SST 52     // solver LDS row stride (208 B, 16B-aligned)

#define AS1 __attribute__((address_space(1)))
#define AS3 __attribute__((address_space(3)))

static __device__ __forceinline__ void gload16(const u16* g, u16* l) {
    __builtin_amdgcn_global_load_lds((const AS1 unsigned int*)g, (AS3 unsigned int*)l, 16, 0, 0);
}

static __device__ __forceinline__ int clamp_pl(int p) {
    if (p < 1) p = 1;
    if (p > TLEN - 1) p = TLEN - 1;
    return p;
}

static __device__ __forceinline__ u16 f2bf(float x) {
    unsigned u = __float_as_uint(x);
    return (u16)((u + 0x7FFFu + ((u >> 16) & 1u)) >> 16);
}
static __device__ __forceinline__ float bf2f(u16 h) {
    return __uint_as_float(((unsigned)h) << 16);
}

// 48-elem dot of two 16B-aligned LDS rows via 12+12 ds_read_b128
static __device__ __forceinline__ float dot48(const float* __restrict__ a,
                                              const float* __restrict__ b) {
    float s0 = 0.f, s1 = 0.f, s2 = 0.f, s3 = 0.f;
#pragma unroll
    for (int m = 0; m < 12; ++m) {
        float4 av = *(const float4*)(a + m * 4);
        float4 bv = *(const float4*)(b + m * 4);
        s0 += av.x * bv.x; s1 += av.y * bv.y;
        s2 += av.z * bv.z; s3 += av.w * bv.w;
    }
    return (s0 + s1) + (s2 + s3);
}

// register-tiled 3x3 block of a 48x48 row.row matmul:
// acc[r][c] = dot(L[i0+r], R[j0+c]), rows 16B-aligned stride SST.
static __device__ __forceinline__ void mm48_3x3(const float* __restrict__ Lb,
                                                const float* __restrict__ Rb,
                                                int i0, int j0, float acc[3][3]) {
#pragma unroll
    for (int r = 0; r < 3; ++r)
#pragma unroll
        for (int c = 0; c < 3; ++c) acc[r][c] = 0.f;
#pragma unroll 4
    for (int m = 0; m < 12; ++m) {
        float4 a0 = *(const float4*)(Lb + (i0 + 0) * SST + m * 4);
        float4 a1 = *(const float4*)(Lb + (i0 + 1) * SST + m * 4);
        float4 a2 = *(const float4*)(Lb + (i0 + 2) * SST + m * 4);
        float4 b0 = *(const float4*)(Rb + (j0 + 0) * SST + m * 4);
        float4 b1 = *(const float4*)(Rb + (j0 + 1) * SST + m * 4);
        float4 b2 = *(const float4*)(Rb + (j0 + 2) * SST + m * 4);
        acc[0][0] += a0.x * b0.x + a0.y * b0.y + a0.z * b0.z + a0.w * b0.w;
        acc[0][1] += a0.x * b1.x + a0.y * b1.y + a0.z * b1.z + a0.w * b1.w;
        acc[0][2] += a0.x * b2.x + a0.y * b2.y + a0.z * b2.z + a0.w * b2.w;
        acc[1][0] += a1.x * b0.x + a1.y * b0.y + a1.z * b0.z + a1.w * b0.w;
        acc[1][1] += a1.x * b1.x + a1.y * b1.y + a1.z * b1.z + a1.w * b1.w;
        acc[1][2] += a1.x * b2.x + a1.y * b2.y + a1.z * b2.z + a1.w * b2.w;
        acc[2][0] += a2.x * b0.x + a2.y * b0.y + a2.z * b0.z + a2.w * b0.w;
        acc[2][1] += a2.x * b1.x + a2.y * b1.y + a2.z * b1.z + a2.w * b1.w;
        acc[2][2] += a2.x * b2.x + a2.y * b2.y + a2.z * b2.z + a2.w * b2.w;
    }
}

#define WB() __builtin_amdgcn_wave_barrier()

// ---------------- LayerNorm -> bf16 hi/lo split ----------------
__global__ __launch_bounds__(256) void ln_kernel(const float* __restrict__ hs,
                                                 const float* __restrict__ g,
                                                 const float* __restrict__ b,
                                                 u16* __restrict__ nh,
                                                 u16* __restrict__ nl)
{
    int row = blockIdx.x;
    int tid = threadIdx.x;
    const float* x = hs + (size_t)row * DDIM;
    float4 v = ((const float4*)x)[tid];
    float s  = v.x + v.y + v.z + v.w;
    float ss = v.x*v.x + v.y*v.y + v.z*v.z + v.w*v.w;
    for (int off = 32; off > 0; off >>= 1) {
        s  += __shfl_down(s, off);
        ss += __shfl_down(ss, off);
    }
    __shared__ float rs[4], rss[4], st[2];
    int wid = tid >> 6, lane = tid & 63;
    if (lane == 0) { rs[wid] = s; rss[wid] = ss; }
    __syncthreads();
    if (tid == 0) {
        float S  = rs[0] + rs[1] + rs[2] + rs[3];
        float SS = rss[0] + rss[1] + rss[2] + rss[3];
        float mu = S / (float)DDIM;
        float var = SS / (float)DDIM - mu * mu;
        st[0] = mu;
        st[1] = rsqrtf(var + LNEPS);
    }
    __syncthreads();
    float mu = st[0], rstd = st[1];
    float4 gv = ((const float4*)g)[tid];
    float4 bv = ((const float4*)b)[tid];
    float o[4];
    o[0] = (v.x - mu) * rstd * gv.x + bv.x;
    o[1] = (v.y - mu) * rstd * gv.y + bv.y;
    o[2] = (v.z - mu) * rstd * gv.z + bv.z;
    o[3] = (v.w - mu) * rstd * gv.w + bv.w;
    u16 h[4], l[4];
#pragma unroll
    for (int i = 0; i < 4; ++i) {
        h[i] = f2bf(o[i]);
        l[i] = f2bf(o[i] - bf2f(h[i]));
    }
    uint2 ph, pl2;
    ph.x = (unsigned)h[0] | ((unsigned)h[1] << 16);
    ph.y = (unsigned)h[2] | ((unsigned)h[3] << 16);
    pl2.x = (unsigned)l[0] | ((unsigned)l[1] << 16);
    pl2.y = (unsigned)l[2] | ((unsigned)l[3] << 16);
    *(uint2*)(nh + (size_t)row * DDIM + tid * 4) = ph;
    *(uint2*)(nl + (size_t)row * DDIM + tid * 4) = pl2;
}

// ---------------- transpose + bf16 hi/lo convert: in[R][C] f32 -> out[C][R] ----------------
__global__ __launch_bounds__(256) void transcvt(const float* __restrict__ in,
                                                u16* __restrict__ oh,
                                                u16* __restrict__ ol,
                                                int R, int C)
{
    __shared__ float t[32][33];
    int bx = blockIdx.x, by = blockIdx.y;
    int tx = threadIdx.x & 31, ty = threadIdx.x >> 5;
#pragma unroll
    for (int j = 0; j < 4; ++j)
        t[ty + j * 8][tx] = in[(size_t)(by * 32 + ty + j * 8) * C + bx * 32 + tx];
    __syncthreads();
#pragma unroll
    for (int j = 0; j < 4; ++j) {
        float v = t[tx][ty + j * 8];
        u16 h = f2bf(v);
        size_t o = (size_t)(bx * 32 + ty + j * 8) * R + by * 32 + tx;
        oh[o] = h;
        ol[o] = f2bf(v - bf2f(h));
    }
}

// ---------------- split-bf16 MFMA GEMM (NT): C[z] = A[z] @ Bt[z]^T ----------------
template<int OMODE>
__global__ __launch_bounds__(256) void gemm_mfma(
    const u16* __restrict__ Ah, const u16* __restrict__ Al, long sAz,
    const u16* __restrict__ Bth, const u16* __restrict__ Btl, long sBz,
    float* __restrict__ C, u16* __restrict__ Oh, u16* __restrict__ Ol, long sCz,
    int M, int N, int K,
    const int* __restrict__ pl_ptr, const float* __restrict__ gate_ptr)
{
    int z = blockIdx.z;
    int m0 = blockIdx.y * 128, n0 = blockIdx.x * 128;
    if (pl_ptr) {
        int p = clamp_pl(pl_ptr[0]);
        if (m0 >= (p < M ? p : M)) return;
    }
    Ah  += (size_t)z * sAz;  Al  += (size_t)z * sAz;
    Bth += (size_t)z * sBz;  Btl += (size_t)z * sBz;

    __shared__ u16 As[2][128][32];
    __shared__ u16 Bs[2][128][32];

    int tid = threadIdx.x;
    int wid = tid >> 6, ln = tid & 63;
    int wm = (wid >> 1) * 64, wn = (wid & 1) * 64;
    int r16 = ln & 15, kg = ln >> 4;

    int rb = wid * 32;
    int lr = ln >> 2;
    int sl = ln & 3;
    int koff = (sl ^ (((rb + lr) >> 1) & 3)) * 8;

    const u16* gA0h = Ah  + (size_t)(m0 + rb + lr) * K + koff;
    const u16* gA1h = gA0h + (size_t)16 * K;
    const u16* gA0l = Al  + (size_t)(m0 + rb + lr) * K + koff;
    const u16* gA1l = gA0l + (size_t)16 * K;
    const u16* gB0h = Bth + (size_t)(n0 + rb + lr) * K + koff;
    const u16* gB1h = gB0h + (size_t)16 * K;
    const u16* gB0l = Btl + (size_t)(n0 + rb + lr) * K + koff;
    const u16* gB1l = gB0l + (size_t)16 * K;

    u16* lA0h = &As[0][rb][0];      u16* lA1h = &As[0][rb + 16][0];
    u16* lA0l = &As[1][rb][0];      u16* lA1l = &As[1][rb + 16][0];
    u16* lB0h = &Bs[0][rb][0];      u16* lB1h = &Bs[0][rb + 16][0];
    u16* lB0l = &Bs[1][rb][0];      u16* lB1l = &Bs[1][rb + 16][0];

    f32x4 acc[4][4];
#pragma unroll
    for (int mt = 0; mt < 4; ++mt)
#pragma unroll
        for (int nt = 0; nt < 4; ++nt)
            acc[mt][nt] = (f32x4){0.f, 0.f, 0.f, 0.f};

    for (int k0 = 0; k0 < K; k0 += 32) {
        __syncthreads();
        gload16(gA0h, lA0h);  gload16(gA1h, lA1h);
        gload16(gA0l, lA0l);  gload16(gA1l, lA1l);
        gload16(gB0h, lB0h);  gload16(gB1h, lB1h);
        gload16(gB0l, lB0l);  gload16(gB1l, lB1l);
        gA0h += 32; gA1h += 32; gA0l += 32; gA1l += 32;
        gB0h += 32; gB1h += 32; gB0l += 32; gB1l += 32;
        __syncthreads();

        bf16x8 bhf[4], blf[4];
#pragma unroll
        for (int nt = 0; nt < 4; ++nt) {
            int r = wn + nt * 16 + r16;
            int s = (kg ^ ((r >> 1) & 3)) * 8;
            bhf[nt] = *(const bf16x8*)&Bs[0][r][s];
            blf[nt] = *(const bf16x8*)&Bs[1][r][s];
        }
#pragma unroll
        for (int mt = 0; mt < 4; ++mt) {
            int r = wm + mt * 16 + r16;
            int s = (kg ^ ((r >> 1) & 3)) * 8;
            bf16x8 ah = *(const bf16x8*)&As[0][r][s];
            bf16x8 al = *(const bf16x8*)&As[1][r][s];
#pragma unroll
            for (int nt = 0; nt < 4; ++nt) {
                acc[mt][nt] = __builtin_amdgcn_mfma_f32_16x16x32_bf16(ah, bhf[nt], acc[mt][nt], 0, 0, 0);
                acc[mt][nt] = __builtin_amdgcn_mfma_f32_16x16x32_bf16(ah, blf[nt], acc[mt][nt], 0, 0, 0);
                acc[mt][nt] = __builtin_amdgcn_mfma_f32_16x16x32_bf16(al, bhf[nt], acc[mt][nt], 0, 0, 0);
            }
        }
    }

    int orow0 = m0 + wm + kg * 4;
    int ocol0 = n0 + wn + r16;
    if (OMODE == 0) {
        float scale = 1.0f;
        if (gate_ptr) scale = 1.0f / (1.0f + expf(-gate_ptr[0]));
        float* Cz = C + (size_t)z * sCz;
#pragma unroll
        for (int mt = 0; mt < 4; ++mt)
#pragma unroll
            for (int nt = 0; nt < 4; ++nt)
#pragma unroll
                for (int j = 0; j < 4; ++j)
                    Cz[(size_t)(orow0 + mt * 16 + j) * N + ocol0 + nt * 16] = acc[mt][nt][j] * scale;
    } else {
        u16* Ohz = Oh + (size_t)z * sCz;
        u16* Olz = Ol + (size_t)z * sCz;
#pragma unroll
        for (int mt = 0; mt < 4; ++mt)
#pragma unroll
            for (int nt = 0; nt < 4; ++nt)
#pragma unroll
                for (int j = 0; j < 4; ++j) {
                    float v = acc[mt][nt][j];
                    u16 h = f2bf(v);
                    size_t o = (size_t)(orow0 + mt * 16 + j) * N + ocol0 + nt * 16;
                    Ohz[o] = h;
                    Olz[o] = f2bf(v - bf2f(h));
                }
    }
}

// ---------------- Gram statistics, 4-way time-split partials (per-k regions) ----------------
// Partial region index = k*GSPLIT + sp; reduction is folded into the solver loads.
__global__ __launch_bounds__(256) void gram_kernel(const float* __restrict__ Kp,
                                                   const float* __restrict__ Vp,
                                                   float* __restrict__ Gpart,
                                                   float* __restrict__ Mpart,
                                                   float* __restrict__ Cpart,
                                                   int k,
                                                   const int* __restrict__ pl_ptr)
{
    int h = blockIdx.x, b = blockIdx.y, sp = blockIdx.z;
    int pl = clamp_pl(pl_ptr[0]);
    int lo = sp * GCHUNK;
    int hi = lo + GCHUNK; if (hi > pl) hi = pl;
    __shared__ float pks[65][48];
    __shared__ float pvs[64][64];
    int tid = threadIdx.x;
    int tx = tid & 15, ty = tid >> 4;
    float gacc[3][3] = {}, macc[3][3] = {}, cacc[4][3] = {};
    const float* Kbase = Kp + (size_t)b * TLEN * HR + h * RDIM;
    const float* Vbase = Vp + (size_t)b * TLEN * HHD + h * HDIM;
    const float4 z4 = make_float4(0.f, 0.f, 0.f, 0.f);

    for (int c0 = lo; c0 < hi; c0 += 64) {
        for (int idx = tid; idx < 65 * 12; idx += 256) {
            int rr = idx / 12, c4 = idx % 12;
            int tg = c0 + rr;
            *(float4*)&pks[rr][c4 * 4] =
                (tg < pl) ? *(const float4*)&Kbase[(size_t)tg * HR + c4 * 4] : z4;
        }
        for (int idx = tid; idx < 64 * 16; idx += 256) {
            int rr = idx >> 4, c4 = idx & 15;
            int tg = c0 + rr;
            *(float4*)&pvs[rr][c4 * 4] =
                (tg < pl) ? *(const float4*)&Vbase[(size_t)tg * HHD + c4 * 4] : z4;
        }
        __syncthreads();
#pragma unroll 2
        for (int l = 0; l < 64; ++l) {
            float a0[3], a1[3], bb[3], vv[4];
#pragma unroll
            for (int i = 0; i < 3; ++i) {
                a0[i] = pks[l][tx * 3 + i];
                a1[i] = pks[l + 1][tx * 3 + i];
                bb[i] = pks[l][ty * 3 + i];
            }
#pragma unroll
            for (int j = 0; j < 4; ++j) vv[j] = pvs[l][ty * 4 + j];
#pragma unroll
            for (int i = 0; i < 3; ++i)
#pragma unroll
                for (int j = 0; j < 3; ++j) {
                    gacc[i][j] += a0[i] * bb[j];
                    macc[i][j] += a1[i] * bb[j];
                }
#pragma unroll
            for (int j = 0; j < 4; ++j)
#pragma unroll
                for (int i = 0; i < 3; ++i)
                    cacc[j][i] += vv[j] * a0[i];
        }
        __syncthreads();
    }
    size_t pbase = (size_t)(k * GSPLIT + sp) * (BSZ * NH) + b * NH + h;
    float* Gp = Gpart + pbase * 2304;
    float* Mp = Mpart + pbase * 2304;
    float* Cp = Cpart + pbase * 3072;
#pragma unroll
    for (int i = 0; i < 3; ++i)
#pragma unroll
        for (int j = 0; j < 3; ++j) {
            Gp[(tx * 3 + i) * 48 + (ty * 3 + j)] = gacc[i][j];
            Mp[(tx * 3 + i) * 48 + (ty * 3 + j)] = macc[i][j];
        }
#pragma unroll
    for (int j = 0; j < 4; ++j)
#pragma unroll
        for (int i = 0; i < 3; ++i)
            Cp[(ty * 4 + j) * 48 + (tx * 3 + i)] = cacc[j][i];
}

// ---------------- per-(k,b,h) solver stage 1: W = scl^2 * P*P*H ----------------
// Loads G,M by summing the 4 time-split partials (deterministic fixed order).
// H = (G+ridge I)^{-1} via Gauss-Jordan (1 barrier/pivot, triangular ranges);
// P = H*M; R = H*M^T; Q = R*P; Q2 = Q*Q; sigma^4 = lambda_max(Q2) by power
// iteration (48 iters == 96 on Q); X = P*H; W = s2*P*X (transposed out).
__global__ __launch_bounds__(256) void solver_kernel(const float* __restrict__ Gpart,
                                                     const float* __restrict__ Mpart,
                                                     float* __restrict__ Wg,
                                                     const float* __restrict__ log_ridges,
                                                     const float* __restrict__ log_gammas)
{
    int blk = blockIdx.x;                 // (k*BSZ + b)*NH + h
    int k = blk / (BSZ * NH);
    int p64 = blk - k * (BSZ * NH);       // b*NH + h
    int tid = threadIdx.x;
    int ti = tid >> 4, tj = tid & 15;
    int i0 = ti * 3, j0 = tj * 3;

    __shared__ float A [48 * SST];        // G -> GJ(D) -> M^T -> R -> Q^T -> X^T
    __shared__ float Hs[48 * SST];        // I -> B -> H = G^{-1}
    __shared__ float Mm[48 * SST];        // M -> Q
    __shared__ float Pm[48 * SST];        // P  (row-major)
    __shared__ float Pt[48 * SST];        // P^T -> Q2
    __shared__ float pvb[4][SST];

    size_t base = (size_t)blk;
    float ridge = expf(log_ridges[k]);

    for (int idx = tid; idx < 2304; idx += 256) {
        int i = idx / 48, j = idx % 48;
        float sg = 0.f, sm = 0.f;
#pragma unroll
        for (int sp = 0; sp < GSPLIT; ++sp) {
            size_t pb = ((size_t)(k * GSPLIT + sp) * (BSZ * NH) + p64);
            sg += Gpart[pb * 2304 + idx];
            sm += Mpart[pb * 2304 + idx];
        }
        A [i * SST + j] = sg + ((i == j) ? ridge : 0.f);
        Hs[i * SST + j] = (i == j) ? 1.f : 0.f;
        Mm[i * SST + j] = sm;
    }
    __syncthreads();

    // ---- Gauss-Jordan, deferred row-scaling, 1 barrier/pivot, triangular ranges ----
    for (int p = 0; p < 48; ++p) {
        int p4 = p >> 2;
        float pr = 1.0f / fmaxf(A[p * SST + p], 1e-30f);   // SPD -> pivot > 0
        int c4a = p4 + 1;              // first full A float4 col-block (> p)
        int nA4 = 11 - p4;             // A blocks [c4a..11]
        int nb  = 3 - (p & 3);         // boundary scalar cols (p+1 .. 4*c4a-1)
        for (int q = tid; q < 576; q += 256) {   // 48 rows x 12 float4 blocks
            int i = q / 12, c = q % 12;
            if (i == p) continue;
            float f = A[i * SST + p] * pr;
            if (c < nA4) {
                int c4 = c4a + c;
                float4 prw = *(const float4*)&A[p * SST + c4 * 4];
                float4* d = (float4*)&A[i * SST + c4 * 4];
                float4 v = *d;
                v.x -= f * prw.x; v.y -= f * prw.y;
                v.z -= f * prw.z; v.w -= f * prw.w;
                *d = v;
            } else {
                int c4 = c - nA4;      // 0 .. p4  (Hs cols <= p; extras are f*0)
                float4 prw = *(const float4*)&Hs[p * SST + c4 * 4];
                float4* d = (float4*)&Hs[i * SST + c4 * 4];
                float4 v = *d;
                v.x -= f * prw.x; v.y -= f * prw.y;
                v.z -= f * prw.z; v.w -= f * prw.w;
                *d = v;
            }
        }
        if (nb) {
            for (int i = tid; i < 48; i += 256) {
                if (i == p) continue;
                float f = A[i * SST + p] * pr;
                for (int c = p + 1; c < 4 * c4a; ++c)
                    A[i * SST + c] -= f * A[p * SST + c];
            }
        }
        __syncthreads();
    }
    // H = D^{-1} B  (row-wise scale by 1/d_i, d_i = A[i][i])
    for (int idx = tid; idx < 2304; idx += 256) {
        int i = idx / 48, j = idx % 48;
        Hs[i * SST + j] /= fmaxf(A[i * SST + i], 1e-30f);
    }
    __syncthreads();
    // ---- M^T into A (GJ remnants dead) ----
    for (int idx = tid; idx < 2304; idx += 256) {
        int i = idx / 48, j = idx % 48;
        A[j * SST + i] = Mm[i * SST + j];
    }
    __syncthreads();
    // ---- P = H*M: tile = dot(Hs rows, Mt=A rows); store Pm and Pt ----
    {
        float acc[3][3];
        mm48_3x3(Hs, A, i0, j0, acc);
#pragma unroll
        for (int r = 0; r < 3; ++r)
#pragma unroll
            for (int c = 0; c < 3; ++c) {
                Pm[(i0 + r) * SST + j0 + c] = acc[r][c];
                Pt[(j0 + c) * SST + i0 + r] = acc[r][c];
            }
    }
    __syncthreads();
    // ---- R = H*M^T into A (Mt dead): dot(Hs rows, Mm rows) ----
    {
        float acc[3][3];
        mm48_3x3(Hs, Mm, i0, j0, acc);
        __syncthreads();                      // Mt reads done before overwriting A
#pragma unroll
        for (int r = 0; r < 3; ++r)
#pragma unroll
            for (int c = 0; c < 3; ++c)
                A[(i0 + r) * SST + j0 + c] = acc[r][c];
    }
    __syncthreads();
    // ---- Q = R*P: dot(A rows, Pt rows) -> Q into Mm (M dead), Q^T into A ----
    {
        float acc[3][3];
        mm48_3x3(A, Pt, i0, j0, acc);
        __syncthreads();                      // R/Pt reads done before overwrite
#pragma unroll
        for (int r = 0; r < 3; ++r)
#pragma unroll
            for (int c = 0; c < 3; ++c) {
                Mm[(i0 + r) * SST + j0 + c] = acc[r][c];
                A [(j0 + c) * SST + i0 + r] = acc[r][c];
            }
    }
    __syncthreads();
    // ---- Q2 = Q*Q: Q2[i][j] = dot(Q[i], Qt[j]) = dot(Mm[i], A[j]) -> into Pt (dead) ----
    {
        float acc[3][3];
        mm48_3x3(Mm, A, i0, j0, acc);
#pragma unroll
        for (int r = 0; r < 3; ++r)
#pragma unroll
            for (int c = 0; c < 3; ++c)
                Pt[(i0 + r) * SST + j0 + c] = acc[r][c];
    }
    __syncthreads();

    // ---- power iteration on Q2 (48 iters == 96 on Q): redundant per wave ----
    int ln = tid & 63, w = tid >> 6;
    float* pv = pvb[w];
    if (ln < 48) pv[ln] = ((float)((ln * 2654435761u) & 0xFFFF)) / 65536.0f + 0.5f;
    WB();
    float lam = 0.f;
    for (int it = 0; it < 49; ++it) {
        float z = 0.f;
        if (ln < 48) z = dot48(&Pt[ln * SST], pv);
        if (it == 48) {
            float nn = z * z;
            for (int off = 1; off < 64; off <<= 1) nn += __shfl_xor(nn, off);
            lam = sqrtf(nn);               // lambda_max(Q2) = sigma_max^4
            break;
        }
        if ((it & 3) == 3) {
            float nn = z * z;
            for (int off = 1; off < 64; off <<= 1) nn += __shfl_xor(nn, off);
            z *= rsqrtf(fmaxf(nn, 1e-30f));
        }
        WB();
        if (ln < 48) pv[ln] = z;
        WB();
    }
    float sigma = sqrtf(sqrtf(fmaxf(lam, 0.f)));
    float gamma = expf(log_gammas[k]);
    float scl = fminf(gamma, 1.f) / fmaxf(fmaxf(sigma, 1e-8f), 1.f);
    float s2 = scl * scl;

    // ---- X^T into A (Qt dead; all waves past the post-Q2 barrier):
    //      X = P*H, H symmetric -> X[i][j] = dot(Pm[i], Hs[j]) ----
    {
        float acc[3][3];
        mm48_3x3(Pm, Hs, i0, j0, acc);
        __syncthreads();                      // power-phase Pt/A reads done
#pragma unroll
        for (int r = 0; r < 3; ++r)
#pragma unroll
            for (int c = 0; c < 3; ++c)
                A[(j0 + c) * SST + i0 + r] = acc[r][c];
    }
    __syncthreads();
    // ---- W = s2*P*X: dot(Pm rows, Xt=A rows); store transposed to global ----
    {
        float acc[3][3];
        mm48_3x3(Pm, A, i0, j0, acc);
#pragma unroll
        for (int r = 0; r < 3; ++r)
#pragma unroll
            for (int c = 0; c < 3; ++c)
                Wg[base * 2304 + (size_t)(j0 + c) * 48 + i0 + r] = s2 * acc[r][c];
    }
}

// ---------------- solver stage 2: F = C_v * W  (64x48 = [64x48][48x48]) ----------------
// C_v loaded by summing the 4 time-split partials; register-tiled 4x3 per thread.
__global__ __launch_bounds__(256) void solver2_kernel(const float* __restrict__ Cpart,
                                                      const float* __restrict__ Wg,
                                                      float* __restrict__ Fb)
{
    int blk = blockIdx.x;
    int k = blk / (BSZ * NH);
    int p64 = blk - k * (BSZ * NH);
    int tid = threadIdx.x;
    int ti = tid >> 4, tj = tid & 15;
    int i0 = ti * 4, j0 = tj * 3;
    __shared__ float CvL[64 * SST];
    __shared__ float WtL[48 * SST];       // row j = W[.][j]
    const float* Wp = Wg + (size_t)blk * 2304;
    for (int idx = tid; idx < 3072; idx += 256) {
        float sc = 0.f;
#pragma unroll
        for (int sp = 0; sp < GSPLIT; ++sp)
            sc += Cpart[((size_t)(k * GSPLIT + sp) * (BSZ * NH) + p64) * 3072 + idx];
        CvL[(idx / 48) * SST + (idx % 48)] = sc;
    }
    for (int idx = tid; idx < 2304; idx += 256)
        WtL[(idx / 48) * SST + (idx % 48)] = Wp[idx];
    __syncthreads();
    float acc[4][3];
#pragma unroll
    for (int r = 0; r < 4; ++r)
#pragma unroll
        for (int c = 0; c < 3; ++c) acc[r][c] = 0.f;
#pragma unroll 4
    for (int m = 0; m < 12; ++m) {
        float4 a0 = *(const float4*)(CvL + (i0 + 0) * SST + m * 4);
        float4 a1 = *(const float4*)(CvL + (i0 + 1) * SST + m * 4);
        float4 a2 = *(const float4*)(CvL + (i0 + 2) * SST + m * 4);
        float4 a3 = *(const float4*)(CvL + (i0 + 3) * SST + m * 4);
        float4 b0 = *(const float4*)(WtL + (j0 + 0) * SST + m * 4);
        float4 b1 = *(const float4*)(WtL + (j0 + 1) * SST + m * 4);
        float4 b2 = *(const float4*)(WtL + (j0 + 2) * SST + m * 4);
        acc[0][0] += a0.x*b0.x + a0.y*b0.y + a0.z*b0.z + a0.w*b0.w;
        acc[0][1] += a0.x*b1.x + a0.y*b1.y + a0.z*b1.z + a0.w*b1.w;
        acc[0][2] += a0.x*b2.x + a0.y*b2.y + a0.z*b2.z + a0.w*b2.w;
        acc[1][0] += a1.x*b0.x + a1.y*b0.y + a1.z*b0.z + a1.w*b0.w;
        acc[1][1] += a1.x*b1.x + a1.y*b1.y + a1.z*b1.z + a1.w*b1.w;
        acc[1][2] += a1.x*b2.x + a1.y*b2.y + a1.z*b2.z + a1.w*b2.w;
        acc[2][0] += a2.x*b0.x + a2.y*b0.y + a2.z*b0.z + a2.w*b0.w;
        acc[2][1] += a2.x*b1.x + a2.y*b1.y + a2.z*b1.z + a2.w*b1.w;
        acc[2][2] += a2.x*b2.x + a2.y*b2.y + a2.z*b2.z + a2.w*b2.w;
        acc[3][0] += a3.x*b0.x + a3.y*b0.y + a3.z*b0.z + a3.w*b0.w;
        acc[3][1] += a3.x*b1.x + a3.y*b1.y + a3.z*b1.z + a3.w*b1.w;
        acc[3][2] += a3.x*b2.x + a3.y*b2.y + a3.z*b2.z + a3.w*b2.w;
    }
#pragma unroll
    for (int r = 0; r < 4; ++r)
#pragma unroll
        for (int c = 0; c < 3; ++c)
            Fb[(size_t)blk * 3072 + (size_t)(i0 + r) * 48 + j0 + c] = acc[r][c];
}

// ---------------- W_cmb build -> bf16 hi/lo ----------------
__global__ __launch_bounds__(256) void wcmb_kernel(const float* __restrict__ WQ,
                                                   const float* __restrict__ Fb,
                                                   const float* __restrict__ gate_alphas,
                                                   u16* __restrict__ Wh,
                                                   u16* __restrict__ Wl)
{
    int dt = blockIdx.x;  // row tile (0..15)
    int h = blockIdx.y, b = blockIdx.z;
    __shared__ float wq[64][49];
    __shared__ float fs[64][49];
    int tid = threadIdx.x;
    int tx = tid & 15, ty = tid >> 4;
    float acc[4][4] = {};
    for (int k = 0; k < NKOPS; ++k) {
        float gate = 1.0f / (1.0f + expf(-gate_alphas[k]));
        for (int idx = tid; idx < 64 * 48; idx += 256) {
            int rr = idx / 48, cc = idx % 48;
            wq[rr][cc] = WQ[((size_t)k * DDIM + dt * 64 + rr) * HR + h * RDIM + cc];
            fs[rr][cc] = gate * Fb[(((size_t)k * BSZ + b) * NH + h) * 3072 + idx];
        }
        __syncthreads();
        for (int r = 0; r < 48; ++r) {
            float a[4], bb[4];
#pragma unroll
            for (int i = 0; i < 4; ++i) { a[i] = wq[tx * 4 + i][r]; bb[i] = fs[ty * 4 + i][r]; }
#pragma unroll
            for (int i = 0; i < 4; ++i)
#pragma unroll
                for (int j = 0; j < 4; ++j)
                    acc[i][j] += a[i] * bb[j];
        }
        __syncthreads();
    }
#pragma unroll
    for (int i = 0; i < 4; ++i)
#pragma unroll
        for (int j = 0; j < 4; ++j) {
            size_t o = ((size_t)b * DDIM + dt * 64 + tx * 4 + i) * HHD + h * HDIM + ty * 4 + j;
            float v = acc[i][j];
            u16 hh = f2bf(v);
            Wh[o] = hh;
            Wl[o] = f2bf(v - bf2f(hh));
        }
}

// ---------------- host launch ----------------
extern "C" void kernel_launch(void* const* d_in, const int* in_sizes, int n_in,
                              void* d_out, int out_size, void* d_ws, size_t ws_size,
                              hipStream_t stream)
{
    const float* hs          = (const float*)d_in[0];
    const float* WK          = (const float*)d_in[1];
    const float* WQ          = (const float*)d_in[2];
    const float* WV          = (const float*)d_in[3];
    const float* WO          = (const float*)d_in[4];
    const float* ln_g        = (const float*)d_in[5];
    const float* ln_b        = (const float*)d_in[6];
    const float* gate_alphas = (const float*)d_in[7];
    const float* gate_alpha  = (const float*)d_in[8];
    const float* log_ridges  = (const float*)d_in[9];
    const float* log_gammas  = (const float*)d_in[10];
    const int*   pl_ptr      = (const int*)d_in[11];
    float* out = (float*)d_out;

    float* wsf = (float*)d_ws;
    u16* n_hi   = (u16*)(wsf + 0);          // 8,388,608 u16
    u16* n_lo   = (u16*)(wsf + 4194304);
    u16* WVt_h  = (u16*)(wsf + 8388608);    // 1,048,576 u16
    u16* WVt_l  = (u16*)(wsf + 8912896);
    u16* WKt_h  = (u16*)(wsf + 9437184);    // 786,432 u16
    u16* WKt_l  = (u16*)(wsf + 9830400);
    float* Vp   = wsf + 10223616;           // 8,388,608 f32
    float* Kp   = wsf + 18612224;           // 6,291,456 f32  (end 24,903,680 f = 95 MiB)
    // aliases (lifetimes disjoint, stream-ordered)
    u16* Wcmb_h  = (u16*)Vp;                // after grams
    u16* Wcmb_l  = (u16*)(Vp + 2097152);
    u16* Wfint_h = (u16*)(Vp + 4194304);
    u16* Wfint_l = (u16*)(Vp + 6291456);
    u16* WOt_h   = (u16*)Kp;                // after grams
    u16* WOt_l   = (u16*)(Kp + 524288);
    float* Fb    = Kp + 1048576;            // 786,432
    float* Wg    = Kp + 1835008;            // 589,824 (all within Kp region)
    // gram partials live in d_out (dead before final GEMM overwrites all of d_out)
    // regions: (k*GSPLIT+sp) in [0,16): G 2,359,296 + M 2,359,296 + C 3,145,728
    float* Gpart = out;
    float* Mpart = out + 2359296;
    float* Cpart = out + 4718592;           // end 7,864,320 < 8,388,608

    ln_kernel<<<BSZ * TLEN, 256, 0, stream>>>(hs, ln_g, ln_b, n_hi, n_lo);

    // WVt = WV^T (hi/lo);  Vp = normed_prefix @ WV
    transcvt<<<dim3(HHD / 32, DDIM / 32), 256, 0, stream>>>(WV, WVt_h, WVt_l, DDIM, HHD);
    gemm_mfma<0><<<dim3(HHD / 128, TLEN / 128, BSZ), 256, 0, stream>>>(
        n_hi, n_lo, (long)TLEN * DDIM, WVt_h, WVt_l, 0,
        Vp, nullptr, nullptr, (long)TLEN * HHD,
        TLEN, HHD, DDIM, pl_ptr, nullptr);

    for (int k = 0; k < NKOPS; ++k) {
        transcvt<<<dim3(HR / 32, DDIM / 32), 256, 0, stream>>>(
            WK + (size_t)k * DDIM * HR, WKt_h, WKt_l, DDIM, HR);
        gemm_mfma<0><<<dim3(HR / 128, TLEN / 128, BSZ), 256, 0, stream>>>(
            n_hi, n_lo, (long)TLEN * DDIM, WKt_h, WKt_l, 0,
            Kp, nullptr, nullptr, (long)TLEN * HR,
            TLEN, HR, DDIM, pl_ptr, nullptr);
        gram_kernel<<<dim3(NH, BSZ, GSPLIT), 256, 0, stream>>>(
            Kp, Vp, Gpart, Mpart, Cpart, k, pl_ptr);
    }

    // WOt = WO^T (into Kp region, now dead)
    transcvt<<<dim3(DDIM / 32, HHD / 32), 256, 0, stream>>>(WO, WOt_h, WOt_l, HHD, DDIM);

    solver_kernel<<<NKOPS * BSZ * NH, 256, 0, stream>>>(Gpart, Mpart, Wg, log_ridges, log_gammas);
    solver2_kernel<<<NKOPS * BSZ * NH, 256, 0, stream>>>(Cpart, Wg, Fb);

    wcmb_kernel<<<dim3(DDIM / 64, NH, BSZ), 256, 0, stream>>>(WQ, Fb, gate_alphas, Wcmb_h, Wcmb_l);

    // Wfint[b] = WO^T @ Wcmb[b]^T  == Wfin[b]^T, written bf16 hi/lo row-major
    gemm_mfma<1><<<dim3(DDIM / 128, DDIM / 128, BSZ), 256, 0, stream>>>(
        WOt_h, WOt_l, 0, Wcmb_h, Wcmb_l, (long)DDIM * HHD,
        nullptr, Wfint_h, Wfint_l, (long)DDIM * DDIM,
        DDIM, DDIM, HHD, nullptr, nullptr);

    // out[b] = sigmoid(gate_alpha) * normed[b] @ Wfin[b]
    gemm_mfma<0><<<dim3(DDIM / 128, TLEN / 128, BSZ), 256, 0, stream>>>(
        n_hi, n_lo, (long)TLEN * DDIM, Wfint_h, Wfint_l, (long)DDIM * DDIM,
        out, nullptr, nullptr, (long)TLEN * DDIM,
        TLEN, DDIM, DDIM, nullptr, gate_alpha);
}

// Round 13
// 652.623 us; speedup vs baseline: 1.1721x; 1.1721x over previous
//
#include <hip/hip_runtime.h>
#include <math.h>

typedef unsigned short u16;
typedef __attribute__((ext_vector_type(8))) short bf16x8;
typedef __attribute__((ext_vector_type(4))) float f32x4;

#define BSZ 4
#define TLEN 2048
#define DDIM 1024
#define NH 16
#define HDIM 64
#define NKOPS 4
#define RDIM 48
#define HR 768     // NH*RDIM
#define HHD 1024   // NH*HDIM
#define LNEPS 1e-5f
#define GSPLIT 16
#define GCHUNK 128
#define SST 52     // solver LDS row stride (208 B, 16B-aligned)

#define AS1 __attribute__((address_space(1)))
#define AS3 __attribute__((address_space(3)))

static __device__ __forceinline__ void gload16(const u16* g, u16* l) {
    __builtin_amdgcn_global_load_lds((const AS1 unsigned int*)g, (AS3 unsigned int*)l, 16, 0, 0);
}

static __device__ __forceinline__ int clamp_pl(int p) {
    if (p < 1) p = 1;
    if (p > TLEN - 1) p = TLEN - 1;
    return p;
}

static __device__ __forceinline__ u16 f2bf(float x) {
    unsigned u = __float_as_uint(x);
    return (u16)((u + 0x7FFFu + ((u >> 16) & 1u)) >> 16);
}
static __device__ __forceinline__ float bf2f(u16 h) {
    return __uint_as_float(((unsigned)h) << 16);
}

// 48-elem dot of two 16B-aligned LDS rows via 12+12 ds_read_b128
static __device__ __forceinline__ float dot48(const float* __restrict__ a,
                                              const float* __restrict__ b) {
    float s0 = 0.f, s1 = 0.f, s2 = 0.f, s3 = 0.f;
#pragma unroll
    for (int m = 0; m < 12; ++m) {
        float4 av = *(const float4*)(a + m * 4);
        float4 bv = *(const float4*)(b + m * 4);
        s0 += av.x * bv.x; s1 += av.y * bv.y;
        s2 += av.z * bv.z; s3 += av.w * bv.w;
    }
    return (s0 + s1) + (s2 + s3);
}

// register-tiled 3x3 block of a 48x48 row.row matmul:
// acc[r][c] = dot(L[i0+r], R[j0+c]), rows 16B-aligned stride SST.
static __device__ __forceinline__ void mm48_3x3(const float* __restrict__ Lb,
                                                const float* __restrict__ Rb,
                                                int i0, int j0, float acc[3][3]) {
#pragma unroll
    for (int r = 0; r < 3; ++r)
#pragma unroll
        for (int c = 0; c < 3; ++c) acc[r][c] = 0.f;
#pragma unroll 4
    for (int m = 0; m < 12; ++m) {
        float4 a0 = *(const float4*)(Lb + (i0 + 0) * SST + m * 4);
        float4 a1 = *(const float4*)(Lb + (i0 + 1) * SST + m * 4);
        float4 a2 = *(const float4*)(Lb + (i0 + 2) * SST + m * 4);
        float4 b0 = *(const float4*)(Rb + (j0 + 0) * SST + m * 4);
        float4 b1 = *(const float4*)(Rb + (j0 + 1) * SST + m * 4);
        float4 b2 = *(const float4*)(Rb + (j0 + 2) * SST + m * 4);
        acc[0][0] += a0.x * b0.x + a0.y * b0.y + a0.z * b0.z + a0.w * b0.w;
        acc[0][1] += a0.x * b1.x + a0.y * b1.y + a0.z * b1.z + a0.w * b1.w;
        acc[0][2] += a0.x * b2.x + a0.y * b2.y + a0.z * b2.z + a0.w * b2.w;
        acc[1][0] += a1.x * b0.x + a1.y * b0.y + a1.z * b0.z + a1.w * b0.w;
        acc[1][1] += a1.x * b1.x + a1.y * b1.y + a1.z * b1.z + a1.w * b1.w;
        acc[1][2] += a1.x * b2.x + a1.y * b2.y + a1.z * b2.z + a1.w * b2.w;
        acc[2][0] += a2.x * b0.x + a2.y * b0.y + a2.z * b0.z + a2.w * b0.w;
        acc[2][1] += a2.x * b1.x + a2.y * b1.y + a2.z * b1.z + a2.w * b1.w;
        acc[2][2] += a2.x * b2.x + a2.y * b2.y + a2.z * b2.z + a2.w * b2.w;
    }
}

#define WB() __builtin_amdgcn_wave_barrier()

// ---------------- LayerNorm -> bf16 hi/lo split ----------------
__global__ __launch_bounds__(256) void ln_kernel(const float* __restrict__ hs,
                                                 const float* __restrict__ g,
                                                 const float* __restrict__ b,
                                                 u16* __restrict__ nh,
                                                 u16* __restrict__ nl)
{
    int row = blockIdx.x;
    int tid = threadIdx.x;
    const float* x = hs + (size_t)row * DDIM;
    float4 v = ((const float4*)x)[tid];
    float s  = v.x + v.y + v.z + v.w;
    float ss = v.x*v.x + v.y*v.y + v.z*v.z + v.w*v.w;
    for (int off = 32; off > 0; off >>= 1) {
        s  += __shfl_down(s, off);
        ss += __shfl_down(ss, off);
    }
    __shared__ float rs[4], rss[4], st[2];
    int wid = tid >> 6, lane = tid & 63;
    if (lane == 0) { rs[wid] = s; rss[wid] = ss; }
    __syncthreads();
    if (tid == 0) {
        float S  = rs[0] + rs[1] + rs[2] + rs[3];
        float SS = rss[0] + rss[1] + rss[2] + rss[3];
        float mu = S / (float)DDIM;
        float var = SS / (float)DDIM - mu * mu;
        st[0] = mu;
        st[1] = rsqrtf(var + LNEPS);
    }
    __syncthreads();
    float mu = st[0], rstd = st[1];
    float4 gv = ((const float4*)g)[tid];
    float4 bv = ((const float4*)b)[tid];
    float o[4];
    o[0] = (v.x - mu) * rstd * gv.x + bv.x;
    o[1] = (v.y - mu) * rstd * gv.y + bv.y;
    o[2] = (v.z - mu) * rstd * gv.z + bv.z;
    o[3] = (v.w - mu) * rstd * gv.w + bv.w;
    u16 h[4], l[4];
#pragma unroll
    for (int i = 0; i < 4; ++i) {
        h[i] = f2bf(o[i]);
        l[i] = f2bf(o[i] - bf2f(h[i]));
    }
    uint2 ph, pl2;
    ph.x = (unsigned)h[0] | ((unsigned)h[1] << 16);
    ph.y = (unsigned)h[2] | ((unsigned)h[3] << 16);
    pl2.x = (unsigned)l[0] | ((unsigned)l[1] << 16);
    pl2.y = (unsigned)l[2] | ((unsigned)l[3] << 16);
    *(uint2*)(nh + (size_t)row * DDIM + tid * 4) = ph;
    *(uint2*)(nl + (size_t)row * DDIM + tid * 4) = pl2;
}

// ---------------- transpose + bf16 hi/lo convert: in[R][C] f32 -> out[C][R] ----------------
__global__ __launch_bounds__(256) void transcvt(const float* __restrict__ in,
                                                u16* __restrict__ oh,
                                                u16* __restrict__ ol,
                                                int R, int C)
{
    __shared__ float t[32][33];
    int bx = blockIdx.x, by = blockIdx.y;
    int tx = threadIdx.x & 31, ty = threadIdx.x >> 5;
#pragma unroll
    for (int j = 0; j < 4; ++j)
        t[ty + j * 8][tx] = in[(size_t)(by * 32 + ty + j * 8) * C + bx * 32 + tx];
    __syncthreads();
#pragma unroll
    for (int j = 0; j < 4; ++j) {
        float v = t[tx][ty + j * 8];
        u16 h = f2bf(v);
        size_t o = (size_t)(bx * 32 + ty + j * 8) * R + by * 32 + tx;
        oh[o] = h;
        ol[o] = f2bf(v - bf2f(h));
    }
}

// ---------------- split-bf16 MFMA GEMM (NT): C[z] = A[z] @ Bt[z]^T ----------------
template<int OMODE>
__global__ __launch_bounds__(256) void gemm_mfma(
    const u16* __restrict__ Ah, const u16* __restrict__ Al, long sAz,
    const u16* __restrict__ Bth, const u16* __restrict__ Btl, long sBz,
    float* __restrict__ C, u16* __restrict__ Oh, u16* __restrict__ Ol, long sCz,
    int M, int N, int K,
    const int* __restrict__ pl_ptr, const float* __restrict__ gate_ptr)
{
    int z = blockIdx.z;
    int m0 = blockIdx.y * 128, n0 = blockIdx.x * 128;
    if (pl_ptr) {
        int p = clamp_pl(pl_ptr[0]);
        if (m0 >= (p < M ? p : M)) return;
    }
    Ah  += (size_t)z * sAz;  Al  += (size_t)z * sAz;
    Bth += (size_t)z * sBz;  Btl += (size_t)z * sBz;

    __shared__ u16 As[2][128][32];
    __shared__ u16 Bs[2][128][32];

    int tid = threadIdx.x;
    int wid = tid >> 6, ln = tid & 63;
    int wm = (wid >> 1) * 64, wn = (wid & 1) * 64;
    int r16 = ln & 15, kg = ln >> 4;

    int rb = wid * 32;
    int lr = ln >> 2;
    int sl = ln & 3;
    int koff = (sl ^ (((rb + lr) >> 1) & 3)) * 8;

    const u16* gA0h = Ah  + (size_t)(m0 + rb + lr) * K + koff;
    const u16* gA1h = gA0h + (size_t)16 * K;
    const u16* gA0l = Al  + (size_t)(m0 + rb + lr) * K + koff;
    const u16* gA1l = gA0l + (size_t)16 * K;
    const u16* gB0h = Bth + (size_t)(n0 + rb + lr) * K + koff;
    const u16* gB1h = gB0h + (size_t)16 * K;
    const u16* gB0l = Btl + (size_t)(n0 + rb + lr) * K + koff;
    const u16* gB1l = gB0l + (size_t)16 * K;

    u16* lA0h = &As[0][rb][0];      u16* lA1h = &As[0][rb + 16][0];
    u16* lA0l = &As[1][rb][0];      u16* lA1l = &As[1][rb + 16][0];
    u16* lB0h = &Bs[0][rb][0];      u16* lB1h = &Bs[0][rb + 16][0];
    u16* lB0l = &Bs[1][rb][0];      u16* lB1l = &Bs[1][rb + 16][0];

    f32x4 acc[4][4];
#pragma unroll
    for (int mt = 0; mt < 4; ++mt)
#pragma unroll
        for (int nt = 0; nt < 4; ++nt)
            acc[mt][nt] = (f32x4){0.f, 0.f, 0.f, 0.f};

    for (int k0 = 0; k0 < K; k0 += 32) {
        __syncthreads();
        gload16(gA0h, lA0h);  gload16(gA1h, lA1h);
        gload16(gA0l, lA0l);  gload16(gA1l, lA1l);
        gload16(gB0h, lB0h);  gload16(gB1h, lB1h);
        gload16(gB0l, lB0l);  gload16(gB1l, lB1l);
        gA0h += 32; gA1h += 32; gA0l += 32; gA1l += 32;
        gB0h += 32; gB1h += 32; gB0l += 32; gB1l += 32;
        __syncthreads();

        bf16x8 bhf[4], blf[4];
#pragma unroll
        for (int nt = 0; nt < 4; ++nt) {
            int r = wn + nt * 16 + r16;
            int s = (kg ^ ((r >> 1) & 3)) * 8;
            bhf[nt] = *(const bf16x8*)&Bs[0][r][s];
            blf[nt] = *(const bf16x8*)&Bs[1][r][s];
        }
#pragma unroll
        for (int mt = 0; mt < 4; ++mt) {
            int r = wm + mt * 16 + r16;
            int s = (kg ^ ((r >> 1) & 3)) * 8;
            bf16x8 ah = *(const bf16x8*)&As[0][r][s];
            bf16x8 al = *(const bf16x8*)&As[1][r][s];
#pragma unroll
            for (int nt = 0; nt < 4; ++nt) {
                acc[mt][nt] = __builtin_amdgcn_mfma_f32_16x16x32_bf16(ah, bhf[nt], acc[mt][nt], 0, 0, 0);
                acc[mt][nt] = __builtin_amdgcn_mfma_f32_16x16x32_bf16(ah, blf[nt], acc[mt][nt], 0, 0, 0);
                acc[mt][nt] = __builtin_amdgcn_mfma_f32_16x16x32_bf16(al, bhf[nt], acc[mt][nt], 0, 0, 0);
            }
        }
    }

    int orow0 = m0 + wm + kg * 4;
    int ocol0 = n0 + wn + r16;
    if (OMODE == 0) {
        float scale = 1.0f;
        if (gate_ptr) scale = 1.0f / (1.0f + expf(-gate_ptr[0]));
        float* Cz = C + (size_t)z * sCz;
#pragma unroll
        for (int mt = 0; mt < 4; ++mt)
#pragma unroll
            for (int nt = 0; nt < 4; ++nt)
#pragma unroll
                for (int j = 0; j < 4; ++j)
                    Cz[(size_t)(orow0 + mt * 16 + j) * N + ocol0 + nt * 16] = acc[mt][nt][j] * scale;
    } else {
        u16* Ohz = Oh + (size_t)z * sCz;
        u16* Olz = Ol + (size_t)z * sCz;
#pragma unroll
        for (int mt = 0; mt < 4; ++mt)
#pragma unroll
            for (int nt = 0; nt < 4; ++nt)
#pragma unroll
                for (int j = 0; j < 4; ++j) {
                    float v = acc[mt][nt][j];
                    u16 h = f2bf(v);
                    size_t o = (size_t)(orow0 + mt * 16 + j) * N + ocol0 + nt * 16;
                    Ohz[o] = h;
                    Olz[o] = f2bf(v - bf2f(h));
                }
    }
}

// ---------------- Gram statistics, 16-way time-split partials ----------------
__global__ __launch_bounds__(256) void gram_kernel(const float* __restrict__ Kp,
                                                   const float* __restrict__ Vp,
                                                   float* __restrict__ Gpart,
                                                   float* __restrict__ Mpart,
                                                   float* __restrict__ Cpart,
                                                   const int* __restrict__ pl_ptr)
{
    int h = blockIdx.x, b = blockIdx.y, sp = blockIdx.z;
    int pl = clamp_pl(pl_ptr[0]);
    int lo = sp * GCHUNK;
    int hi = lo + GCHUNK; if (hi > pl) hi = pl;
    __shared__ float pks[65][48];
    __shared__ float pvs[64][64];
    int tid = threadIdx.x;
    int tx = tid & 15, ty = tid >> 4;
    float gacc[3][3] = {}, macc[3][3] = {}, cacc[4][3] = {};
    const float* Kbase = Kp + (size_t)b * TLEN * HR + h * RDIM;
    const float* Vbase = Vp + (size_t)b * TLEN * HHD + h * HDIM;
    const float4 z4 = make_float4(0.f, 0.f, 0.f, 0.f);

    for (int c0 = lo; c0 < hi; c0 += 64) {
        for (int idx = tid; idx < 65 * 12; idx += 256) {
            int rr = idx / 12, c4 = idx % 12;
            int tg = c0 + rr;
            *(float4*)&pks[rr][c4 * 4] =
                (tg < pl) ? *(const float4*)&Kbase[(size_t)tg * HR + c4 * 4] : z4;
        }
        for (int idx = tid; idx < 64 * 16; idx += 256) {
            int rr = idx >> 4, c4 = idx & 15;
            int tg = c0 + rr;
            *(float4*)&pvs[rr][c4 * 4] =
                (tg < pl) ? *(const float4*)&Vbase[(size_t)tg * HHD + c4 * 4] : z4;
        }
        __syncthreads();
#pragma unroll 2
        for (int l = 0; l < 64; ++l) {
            float a0[3], a1[3], bb[3], vv[4];
#pragma unroll
            for (int i = 0; i < 3; ++i) {
                a0[i] = pks[l][tx * 3 + i];
                a1[i] = pks[l + 1][tx * 3 + i];
                bb[i] = pks[l][ty * 3 + i];
            }
#pragma unroll
            for (int j = 0; j < 4; ++j) vv[j] = pvs[l][ty * 4 + j];
#pragma unroll
            for (int i = 0; i < 3; ++i)
#pragma unroll
                for (int j = 0; j < 3; ++j) {
                    gacc[i][j] += a0[i] * bb[j];
                    macc[i][j] += a1[i] * bb[j];
                }
#pragma unroll
            for (int j = 0; j < 4; ++j)
#pragma unroll
                for (int i = 0; i < 3; ++i)
                    cacc[j][i] += vv[j] * a0[i];
        }
        __syncthreads();
    }
    size_t pbase = (size_t)sp * (BSZ * NH) + b * NH + h;
    float* Gp = Gpart + pbase * 2304;
    float* Mp = Mpart + pbase * 2304;
    float* Cp = Cpart + pbase * 3072;
#pragma unroll
    for (int i = 0; i < 3; ++i)
#pragma unroll
        for (int j = 0; j < 3; ++j) {
            Gp[(tx * 3 + i) * 48 + (ty * 3 + j)] = gacc[i][j];
            Mp[(tx * 3 + i) * 48 + (ty * 3 + j)] = macc[i][j];
        }
#pragma unroll
    for (int j = 0; j < 4; ++j)
#pragma unroll
        for (int i = 0; i < 3; ++i)
            Cp[(ty * 4 + j) * 48 + (tx * 3 + i)] = cacc[j][i];
}

// reduce GSPLIT partials into the per-k slot of Gb/Mb/Cb
__global__ __launch_bounds__(256) void gram_reduce(const float* __restrict__ Gpart,
                                                   const float* __restrict__ Mpart,
                                                   const float* __restrict__ Cpart,
                                                   float* __restrict__ Gb,
                                                   float* __restrict__ Mb,
                                                   float* __restrict__ Cb,
                                                   int k)
{
    int p = blockIdx.x;               // b*NH+h
    size_t ob = ((size_t)k * (BSZ * NH) + p);
    for (int idx = threadIdx.x; idx < 2304; idx += 256) {
        float sg = 0.f, sm = 0.f;
#pragma unroll
        for (int sp = 0; sp < GSPLIT; ++sp) {
            size_t pb = ((size_t)sp * (BSZ * NH) + p);
            sg += Gpart[pb * 2304 + idx];
            sm += Mpart[pb * 2304 + idx];
        }
        Gb[ob * 2304 + idx] = sg;
        Mb[ob * 2304 + idx] = sm;
    }
    for (int idx = threadIdx.x; idx < 3072; idx += 256) {
        float sc = 0.f;
#pragma unroll
        for (int sp = 0; sp < GSPLIT; ++sp)
            sc += Cpart[((size_t)sp * (BSZ * NH) + p) * 3072 + idx];
        Cb[ob * 3072 + idx] = sc;
    }
}

// ---------------- per-(k,b,h) solver stage 1: W = scl^2 * P*P*H ----------------
// H = (G+ridge I)^{-1} via Gauss-Jordan: 1 barrier/pivot, triangular column ranges.
// P = H*M; R = H*M^T; Q = R*P; Q2 = Q*Q; sigma^4 = lambda_max(Q2) by power
// iteration (48 iters == 96 on Q); X = P*H; W = s2*P*X (transposed out).
__global__ __launch_bounds__(256) void solver_kernel(const float* __restrict__ Gb,
                                                     const float* __restrict__ Mb,
                                                     float* __restrict__ Wg,
                                                     const float* __restrict__ log_ridges,
                                                     const float* __restrict__ log_gammas)
{
    int blk = blockIdx.x;                 // (k*BSZ + b)*NH + h
    int k = blk / (BSZ * NH);
    int tid = threadIdx.x;
    int ti = tid >> 4, tj = tid & 15;
    int i0 = ti * 3, j0 = tj * 3;

    __shared__ float A [48 * SST];        // G -> GJ(D) -> M^T -> R -> Q^T -> X^T
    __shared__ float Hs[48 * SST];        // I -> B -> H = G^{-1}
    __shared__ float Mm[48 * SST];        // M -> Q
    __shared__ float Pm[48 * SST];        // P  (row-major)
    __shared__ float Pt[48 * SST];        // P^T -> Q2
    __shared__ float pvb[4][SST];

    size_t base = (size_t)blk;
    const float* Gp = Gb + base * 2304;
    const float* Mp = Mb + base * 2304;
    float ridge = expf(log_ridges[k]);

    for (int idx = tid; idx < 2304; idx += 256) {
        int i = idx / 48, j = idx % 48;
        A [i * SST + j] = Gp[idx] + ((i == j) ? ridge : 0.f);
        Hs[i * SST + j] = (i == j) ? 1.f : 0.f;
        Mm[i * SST + j] = Mp[idx];
    }
    __syncthreads();

    // ---- Gauss-Jordan, deferred row-scaling, 1 barrier/pivot, triangular ranges ----
    for (int p = 0; p < 48; ++p) {
        int p4 = p >> 2;
        float pr = 1.0f / fmaxf(A[p * SST + p], 1e-30f);   // SPD -> pivot > 0
        int c4a = p4 + 1;              // first full A float4 col-block (> p)
        int nA4 = 11 - p4;             // A blocks [c4a..11]
        int nb  = 3 - (p & 3);         // boundary scalar cols (p+1 .. 4*c4a-1)
        for (int q = tid; q < 576; q += 256) {   // 48 rows x 12 float4 blocks
            int i = q / 12, c = q % 12;
            if (i == p) continue;
            float f = A[i * SST + p] * pr;
            if (c < nA4) {
                int c4 = c4a + c;
                float4 prw = *(const float4*)&A[p * SST + c4 * 4];
                float4* d = (float4*)&A[i * SST + c4 * 4];
                float4 v = *d;
                v.x -= f * prw.x; v.y -= f * prw.y;
                v.z -= f * prw.z; v.w -= f * prw.w;
                *d = v;
            } else {
                int c4 = c - nA4;      // 0 .. p4  (Hs cols <= p; extras are f*0)
                float4 prw = *(const float4*)&Hs[p * SST + c4 * 4];
                float4* d = (float4*)&Hs[i * SST + c4 * 4];
                float4 v = *d;
                v.x -= f * prw.x; v.y -= f * prw.y;
                v.z -= f * prw.z; v.w -= f * prw.w;
                *d = v;
            }
        }
        if (nb) {
            for (int i = tid; i < 48; i += 256) {
                if (i == p) continue;
                float f = A[i * SST + p] * pr;
                for (int c = p + 1; c < 4 * c4a; ++c)
                    A[i * SST + c] -= f * A[p * SST + c];
            }
        }
        __syncthreads();
    }
    // H = D^{-1} B  (row-wise scale by 1/d_i, d_i = A[i][i])
    for (int idx = tid; idx < 2304; idx += 256) {
        int i = idx / 48, j = idx % 48;
        Hs[i * SST + j] /= fmaxf(A[i * SST + i], 1e-30f);
    }
    __syncthreads();
    // ---- M^T into A (GJ remnants dead) ----
    for (int idx = tid; idx < 2304; idx += 256) {
        int i = idx / 48, j = idx % 48;
        A[j * SST + i] = Mm[i * SST + j];
    }
    __syncthreads();
    // ---- P = H*M: tile = dot(Hs rows, Mt=A rows); store Pm and Pt ----
    {
        float acc[3][3];
        mm48_3x3(Hs, A, i0, j0, acc);
#pragma unroll
        for (int r = 0; r < 3; ++r)
#pragma unroll
            for (int c = 0; c < 3; ++c) {
                Pm[(i0 + r) * SST + j0 + c] = acc[r][c];
                Pt[(j0 + c) * SST + i0 + r] = acc[r][c];
            }
    }
    __syncthreads();
    // ---- R = H*M^T into A (Mt dead): dot(Hs rows, Mm rows) ----
    {
        float acc[3][3];
        mm48_3x3(Hs, Mm, i0, j0, acc);
        __syncthreads();                      // Mt reads done before overwriting A
#pragma unroll
        for (int r = 0; r < 3; ++r)
#pragma unroll
            for (int c = 0; c < 3; ++c)
                A[(i0 + r) * SST + j0 + c] = acc[r][c];
    }
    __syncthreads();
    // ---- Q = R*P: dot(A rows, Pt rows) -> Q into Mm (M dead), Q^T into A ----
    {
        float acc[3][3];
        mm48_3x3(A, Pt, i0, j0, acc);
        __syncthreads();                      // R/Pt reads done before overwrite
#pragma unroll
        for (int r = 0; r < 3; ++r)
#pragma unroll
            for (int c = 0; c < 3; ++c) {
                Mm[(i0 + r) * SST + j0 + c] = acc[r][c];
                A [(j0 + c) * SST + i0 + r] = acc[r][c];
            }
    }
    __syncthreads();
    // ---- Q2 = Q*Q: Q2[i][j] = dot(Q[i], Qt[j]) = dot(Mm[i], A[j]) -> into Pt (dead) ----
    {
        float acc[3][3];
        mm48_3x3(Mm, A, i0, j0, acc);
#pragma unroll
        for (int r = 0; r < 3; ++r)
#pragma unroll
            for (int c = 0; c < 3; ++c)
                Pt[(i0 + r) * SST + j0 + c] = acc[r][c];
    }
    __syncthreads();

    // ---- power iteration on Q2 (48 iters == 96 on Q): redundant per wave ----
    int ln = tid & 63, w = tid >> 6;
    float* pv = pvb[w];
    if (ln < 48) pv[ln] = ((float)((ln * 2654435761u) & 0xFFFF)) / 65536.0f + 0.5f;
    WB();
    float lam = 0.f;
    for (int it = 0; it < 49; ++it) {
        float z = 0.f;
        if (ln < 48) z = dot48(&Pt[ln * SST], pv);
        if (it == 48) {
            float nn = z * z;
            for (int off = 1; off < 64; off <<= 1) nn += __shfl_xor(nn, off);
            lam = sqrtf(nn);               // lambda_max(Q2) = sigma_max^4
            break;
        }
        if ((it & 3) == 3) {
            float nn = z * z;
            for (int off = 1; off < 64; off <<= 1) nn += __shfl_xor(nn, off);
            z *= rsqrtf(fmaxf(nn, 1e-30f));
        }
        WB();
        if (ln < 48) pv[ln] = z;
        WB();
    }
    float sigma = sqrtf(sqrtf(fmaxf(lam, 0.f)));
    float gamma = expf(log_gammas[k]);
    float scl = fminf(gamma, 1.f) / fmaxf(fmaxf(sigma, 1e-8f), 1.f);
    float s2 = scl * scl;

    // ---- X^T into A (Qt dead; all waves past the post-Q2 barrier):
    //      X = P*H, H symmetric -> X[i][j] = dot(Pm[i], Hs[j]) ----
    {
        float acc[3][3];
        mm48_3x3(Pm, Hs, i0, j0, acc);
        __syncthreads();                      // power-phase Pt/A reads done
#pragma unroll
        for (int r = 0; r < 3; ++r)
#pragma unroll
            for (int c = 0; c < 3; ++c)
                A[(j0 + c) * SST + i0 + r] = acc[r][c];
    }
    __syncthreads();
    // ---- W = s2*P*X: dot(Pm rows, Xt=A rows); store transposed to global ----
    {
        float acc[3][3];
        mm48_3x3(Pm, A, i0, j0, acc);
#pragma unroll
        for (int r = 0; r < 3; ++r)
#pragma unroll
            for (int c = 0; c < 3; ++c)
                Wg[base * 2304 + (size_t)(j0 + c) * 48 + i0 + r] = s2 * acc[r][c];
    }
}

// ---------------- solver stage 2: F = C_v * W  (64x48 = [64x48][48x48]) ----------------
// register-tiled 4x3 per thread.
__global__ __launch_bounds__(256) void solver2_kernel(const float* __restrict__ Cb,
                                                      const float* __restrict__ Wg,
                                                      float* __restrict__ Fb)
{
    int blk = blockIdx.x;
    int tid = threadIdx.x;
    int ti = tid >> 4, tj = tid & 15;
    int i0 = ti * 4, j0 = tj * 3;
    __shared__ float CvL[64 * SST];
    __shared__ float WtL[48 * SST];       // row j = W[.][j]
    const float* Cp = Cb + (size_t)blk * 3072;
    const float* Wp = Wg + (size_t)blk * 2304;
    for (int idx = tid; idx < 3072; idx += 256)
        CvL[(idx / 48) * SST + (idx % 48)] = Cp[idx];
    for (int idx = tid; idx < 2304; idx += 256)
        WtL[(idx / 48) * SST + (idx % 48)] = Wp[idx];
    __syncthreads();
    float acc[4][3];
#pragma unroll
    for (int r = 0; r < 4; ++r)
#pragma unroll
        for (int c = 0; c < 3; ++c) acc[r][c] = 0.f;
#pragma unroll 4
    for (int m = 0; m < 12; ++m) {
        float4 a0 = *(const float4*)(CvL + (i0 + 0) * SST + m * 4);
        float4 a1 = *(const float4*)(CvL + (i0 + 1) * SST + m * 4);
        float4 a2 = *(const float4*)(CvL + (i0 + 2) * SST + m * 4);
        float4 a3 = *(const float4*)(CvL + (i0 + 3) * SST + m * 4);
        float4 b0 = *(const float4*)(WtL + (j0 + 0) * SST + m * 4);
        float4 b1 = *(const float4*)(WtL + (j0 + 1) * SST + m * 4);
        float4 b2 = *(const float4*)(WtL + (j0 + 2) * SST + m * 4);
        acc[0][0] += a0.x*b0.x + a0.y*b0.y + a0.z*b0.z + a0.w*b0.w;
        acc[0][1] += a0.x*b1.x + a0.y*b1.y + a0.z*b1.z + a0.w*b1.w;
        acc[0][2] += a0.x*b2.x + a0.y*b2.y + a0.z*b2.z + a0.w*b2.w;
        acc[1][0] += a1.x*b0.x + a1.y*b0.y + a1.z*b0.z + a1.w*b0.w;
        acc[1][1] += a1.x*b1.x + a1.y*b1.y + a1.z*b1.z + a1.w*b1.w;
        acc[1][2] += a1.x*b2.x + a1.y*b2.y + a1.z*b2.z + a1.w*b2.w;
        acc[2][0] += a2.x*b0.x + a2.y*b0.y + a2.z*b0.z + a2.w*b0.w;
        acc[2][1] += a2.x*b1.x + a2.y*b1.y + a2.z*b1.z + a2.w*b1.w;
        acc[2][2] += a2.x*b2.x + a2.y*b2.y + a2.z*b2.z + a2.w*b2.w;
        acc[3][0] += a3.x*b0.x + a3.y*b0.y + a3.z*b0.z + a3.w*b0.w;
        acc[3][1] += a3.x*b1.x + a3.y*b1.y + a3.z*b1.z + a3.w*b1.w;
        acc[3][2] += a3.x*b2.x + a3.y*b2.y + a3.z*b2.z + a3.w*b2.w;
    }
#pragma unroll
    for (int r = 0; r < 4; ++r)
#pragma unroll
        for (int c = 0; c < 3; ++c)
            Fb[(size_t)blk * 3072 + (size_t)(i0 + r) * 48 + j0 + c] = acc[r][c];
}

// ---------------- W_cmb build -> bf16 hi/lo ----------------
__global__ __launch_bounds__(256) void wcmb_kernel(const float* __restrict__ WQ,
                                                   const float* __restrict__ Fb,
                                                   const float* __restrict__ gate_alphas,
                                                   u16* __restrict__ Wh,
                                                   u16* __restrict__ Wl)
{
    int dt = blockIdx.x;  // row tile (0..15)
    int h = blockIdx.y, b = blockIdx.z;
    __shared__ float wq[64][49];
    __shared__ float fs[64][49];
    int tid = threadIdx.x;
    int tx = tid & 15, ty = tid >> 4;
    float acc[4][4] = {};
    for (int k = 0; k < NKOPS; ++k) {
        float gate = 1.0f / (1.0f + expf(-gate_alphas[k]));
        for (int idx = tid; idx < 64 * 48; idx += 256) {
            int rr = idx / 48, cc = idx % 48;
            wq[rr][cc] = WQ[((size_t)k * DDIM + dt * 64 + rr) * HR + h * RDIM + cc];
            fs[rr][cc] = gate * Fb[(((size_t)k * BSZ + b) * NH + h) * 3072 + idx];
        }
        __syncthreads();
        for (int r = 0; r < 48; ++r) {
            float a[4], bb[4];
#pragma unroll
            for (int i = 0; i < 4; ++i) { a[i] = wq[tx * 4 + i][r]; bb[i] = fs[ty * 4 + i][r]; }
#pragma unroll
            for (int i = 0; i < 4; ++i)
#pragma unroll
                for (int j = 0; j < 4; ++j)
                    acc[i][j] += a[i] * bb[j];
        }
        __syncthreads();
    }
#pragma unroll
    for (int i = 0; i < 4; ++i)
#pragma unroll
        for (int j = 0; j < 4; ++j) {
            size_t o = ((size_t)b * DDIM + dt * 64 + tx * 4 + i) * HHD + h * HDIM + ty * 4 + j;
            float v = acc[i][j];
            u16 hh = f2bf(v);
            Wh[o] = hh;
            Wl[o] = f2bf(v - bf2f(hh));
        }
}

// ---------------- host launch ----------------
extern "C" void kernel_launch(void* const* d_in, const int* in_sizes, int n_in,
                              void* d_out, int out_size, void* d_ws, size_t ws_size,
                              hipStream_t stream)
{
    const float* hs          = (const float*)d_in[0];
    const float* WK          = (const float*)d_in[1];
    const float* WQ          = (const float*)d_in[2];
    const float* WV          = (const float*)d_in[3];
    const float* WO          = (const float*)d_in[4];
    const float* ln_g        = (const float*)d_in[5];
    const float* ln_b        = (const float*)d_in[6];
    const float* gate_alphas = (const float*)d_in[7];
    const float* gate_alpha  = (const float*)d_in[8];
    const float* log_ridges  = (const float*)d_in[9];
    const float* log_gammas  = (const float*)d_in[10];
    const int*   pl_ptr      = (const int*)d_in[11];
    float* out = (float*)d_out;

    float* wsf = (float*)d_ws;
    u16* n_hi   = (u16*)(wsf + 0);          // 8,388,608 u16
    u16* n_lo   = (u16*)(wsf + 4194304);
    u16* WVt_h  = (u16*)(wsf + 8388608);    // 1,048,576 u16
    u16* WVt_l  = (u16*)(wsf + 8912896);
    u16* WKt_h  = (u16*)(wsf + 9437184);    // 786,432 u16
    u16* WKt_l  = (u16*)(wsf + 9830400);
    float* Vp   = wsf + 10223616;           // 8,388,608 f32
    float* Kp   = wsf + 18612224;           // 6,291,456 f32
    float* Gb   = wsf + 24903680;           // 589,824
    float* Mb   = wsf + 25493504;           // 589,824
    float* Cb   = wsf + 26083328;           // 786,432  (end: 26,869,760 f = 102.5 MiB)
    // aliases (lifetimes disjoint, stream-ordered)
    u16* Wcmb_h  = (u16*)Vp;                // after grams
    u16* Wcmb_l  = (u16*)(Vp + 2097152);
    u16* Wfint_h = (u16*)(Vp + 4194304);
    u16* Wfint_l = (u16*)(Vp + 6291456);
    u16* WOt_h   = (u16*)Kp;                // after grams
    u16* WOt_l   = (u16*)(Kp + 524288);
    float* Fb    = Kp + 1048576;            // 786,432
    float* Wg    = Kp + 1835008;            // 589,824 (all within Kp region)
    // gram partials live in d_out (dead before final GEMM overwrites all of d_out)
    float* Gpart = out;                     // 16*64*2304 = 2,359,296
    float* Mpart = out + 2359296;           // 2,359,296
    float* Cpart = out + 4718592;           // 16*64*3072 = 3,145,728 (end 7,864,320 < 8,388,608)

    ln_kernel<<<BSZ * TLEN, 256, 0, stream>>>(hs, ln_g, ln_b, n_hi, n_lo);

    // WVt = WV^T (hi/lo);  Vp = normed_prefix @ WV
    transcvt<<<dim3(HHD / 32, DDIM / 32), 256, 0, stream>>>(WV, WVt_h, WVt_l, DDIM, HHD);
    gemm_mfma<0><<<dim3(HHD / 128, TLEN / 128, BSZ), 256, 0, stream>>>(
        n_hi, n_lo, (long)TLEN * DDIM, WVt_h, WVt_l, 0,
        Vp, nullptr, nullptr, (long)TLEN * HHD,
        TLEN, HHD, DDIM, pl_ptr, nullptr);

    for (int k = 0; k < NKOPS; ++k) {
        transcvt<<<dim3(HR / 32, DDIM / 32), 256, 0, stream>>>(
            WK + (size_t)k * DDIM * HR, WKt_h, WKt_l, DDIM, HR);
        gemm_mfma<0><<<dim3(HR / 128, TLEN / 128, BSZ), 256, 0, stream>>>(
            n_hi, n_lo, (long)TLEN * DDIM, WKt_h, WKt_l, 0,
            Kp, nullptr, nullptr, (long)TLEN * HR,
            TLEN, HR, DDIM, pl_ptr, nullptr);
        gram_kernel<<<dim3(NH, BSZ, GSPLIT), 256, 0, stream>>>(Kp, Vp, Gpart, Mpart, Cpart, pl_ptr);
        gram_reduce<<<BSZ * NH, 256, 0, stream>>>(Gpart, Mpart, Cpart, Gb, Mb, Cb, k);
    }

    // WOt = WO^T (into Kp region, now dead)
    transcvt<<<dim3(DDIM / 32, HHD / 32), 256, 0, stream>>>(WO, WOt_h, WOt_l, HHD, DDIM);

    solver_kernel<<<NKOPS * BSZ * NH, 256, 0, stream>>>(Gb, Mb, Wg, log_ridges, log_gammas);
    solver2_kernel<<<NKOPS * BSZ * NH, 256, 0, stream>>>(Cb, Wg, Fb);

    wcmb_kernel<<<dim3(DDIM / 64, NH, BSZ), 256, 0, stream>>>(WQ, Fb, gate_alphas, Wcmb_h, Wcmb_l);

    // Wfint[b] = WO^T @ Wcmb[b]^T  == Wfin[b]^T, written bf16 hi/lo row-major
    gemm_mfma<1><<<dim3(DDIM / 128, DDIM / 128, BSZ), 256, 0, stream>>>(
        WOt_h, WOt_l, 0, Wcmb_h, Wcmb_l, (long)DDIM * HHD,
        nullptr, Wfint_h, Wfint_l, (long)DDIM * DDIM,
        DDIM, DDIM, HHD, nullptr, nullptr);

    // out[b] = sigmoid(gate_alpha) * normed[b] @ Wfin[b]
    gemm_mfma<0><<<dim3(DDIM / 128, TLEN / 128, BSZ), 256, 0, stream>>>(
        n_hi, n_lo, (long)TLEN * DDIM, Wfint_h, Wfint_l, (long)DDIM * DDIM,
        out, nullptr, nullptr, (long)TLEN * DDIM,
        TLEN, DDIM, DDIM, nullptr, gate_alpha);
}

// Round 14
// 647.609 us; speedup vs baseline: 1.1811x; 1.0077x over previous
//
#include <hip/hip_runtime.h>
#include <math.h>

typedef unsigned short u16;
typedef __attribute__((ext_vector_type(8))) short bf16x8;
typedef __attribute__((ext_vector_type(4))) float f32x4;

#define BSZ 4
#define TLEN 2048
#define DDIM 1024
#define NH 16
#define HDIM 64
#define NKOPS 4
#define RDIM 48
#define HR 768     // NH*RDIM
#define HHD 1024   // NH*HDIM
#define LNEPS 1e-5f
#define GSPLIT 16
#define SST 52     // solver LDS row stride (208 B, 16B-aligned)

#define AS1 __attribute__((address_space(1)))
#define AS3 __attribute__((address_space(3)))

static __device__ __forceinline__ void gload16(const u16* g, u16* l) {
    __builtin_amdgcn_global_load_lds((const AS1 unsigned int*)g, (AS3 unsigned int*)l, 16, 0, 0);
}

static __device__ __forceinline__ int clamp_pl(int p) {
    if (p < 1) p = 1;
    if (p > TLEN - 1) p = TLEN - 1;
    return p;
}

static __device__ __forceinline__ u16 f2bf(float x) {
    unsigned u = __float_as_uint(x);
    return (u16)((u + 0x7FFFu + ((u >> 16) & 1u)) >> 16);
}
static __device__ __forceinline__ float bf2f(u16 h) {
    return __uint_as_float(((unsigned)h) << 16);
}

// 48-elem dot of two 16B-aligned LDS rows via 12+12 ds_read_b128
static __device__ __forceinline__ float dot48(const float* __restrict__ a,
                                              const float* __restrict__ b) {
    float s0 = 0.f, s1 = 0.f, s2 = 0.f, s3 = 0.f;
#pragma unroll
    for (int m = 0; m < 12; ++m) {
        float4 av = *(const float4*)(a + m * 4);
        float4 bv = *(const float4*)(b + m * 4);
        s0 += av.x * bv.x; s1 += av.y * bv.y;
        s2 += av.z * bv.z; s3 += av.w * bv.w;
    }
    return (s0 + s1) + (s2 + s3);
}

// register-tiled 3x3 block of a 48x48 row.row matmul:
// acc[r][c] = dot(L[i0+r], R[j0+c]), rows 16B-aligned stride SST.
static __device__ __forceinline__ void mm48_3x3(const float* __restrict__ Lb,
                                                const float* __restrict__ Rb,
                                                int i0, int j0, float acc[3][3]) {
#pragma unroll
    for (int r = 0; r < 3; ++r)
#pragma unroll
        for (int c = 0; c < 3; ++c) acc[r][c] = 0.f;
#pragma unroll 4
    for (int m = 0; m < 12; ++m) {
        float4 a0 = *(const float4*)(Lb + (i0 + 0) * SST + m * 4);
        float4 a1 = *(const float4*)(Lb + (i0 + 1) * SST + m * 4);
        float4 a2 = *(const float4*)(Lb + (i0 + 2) * SST + m * 4);
        float4 b0 = *(const float4*)(Rb + (j0 + 0) * SST + m * 4);
        float4 b1 = *(const float4*)(Rb + (j0 + 1) * SST + m * 4);
        float4 b2 = *(const float4*)(Rb + (j0 + 2) * SST + m * 4);
        acc[0][0] += a0.x * b0.x + a0.y * b0.y + a0.z * b0.z + a0.w * b0.w;
        acc[0][1] += a0.x * b1.x + a0.y * b1.y + a0.z * b1.z + a0.w * b1.w;
        acc[0][2] += a0.x * b2.x + a0.y * b2.y + a0.z * b2.z + a0.w * b2.w;
        acc[1][0] += a1.x * b0.x + a1.y * b0.y + a1.z * b0.z + a1.w * b0.w;
        acc[1][1] += a1.x * b1.x + a1.y * b1.y + a1.z * b1.z + a1.w * b1.w;
        acc[1][2] += a1.x * b2.x + a1.y * b2.y + a1.z * b2.z + a1.w * b2.w;
        acc[2][0] += a2.x * b0.x + a2.y * b0.y + a2.z * b0.z + a2.w * b0.w;
        acc[2][1] += a2.x * b1.x + a2.y * b1.y + a2.z * b1.z + a2.w * b1.w;
        acc[2][2] += a2.x * b2.x + a2.y * b2.y + a2.z * b2.z + a2.w * b2.w;
    }
}

#define WB() __builtin_amdgcn_wave_barrier()

// ---------------- LayerNorm -> bf16 hi/lo split ----------------
__global__ __launch_bounds__(256) void ln_kernel(const float* __restrict__ hs,
                                                 const float* __restrict__ g,
                                                 const float* __restrict__ b,
                                                 u16* __restrict__ nh,
                                                 u16* __restrict__ nl)
{
    int row = blockIdx.x;
    int tid = threadIdx.x;
    const float* x = hs + (size_t)row * DDIM;
    float4 v = ((const float4*)x)[tid];
    float s  = v.x + v.y + v.z + v.w;
    float ss = v.x*v.x + v.y*v.y + v.z*v.z + v.w*v.w;
    for (int off = 32; off > 0; off >>= 1) {
        s  += __shfl_down(s, off);
        ss += __shfl_down(ss, off);
    }
    __shared__ float rs[4], rss[4], st[2];
    int wid = tid >> 6, lane = tid & 63;
    if (lane == 0) { rs[wid] = s; rss[wid] = ss; }
    __syncthreads();
    if (tid == 0) {
        float S  = rs[0] + rs[1] + rs[2] + rs[3];
        float SS = rss[0] + rss[1] + rss[2] + rss[3];
        float mu = S / (float)DDIM;
        float var = SS / (float)DDIM - mu * mu;
        st[0] = mu;
        st[1] = rsqrtf(var + LNEPS);
    }
    __syncthreads();
    float mu = st[0], rstd = st[1];
    float4 gv = ((const float4*)g)[tid];
    float4 bv = ((const float4*)b)[tid];
    float o[4];
    o[0] = (v.x - mu) * rstd * gv.x + bv.x;
    o[1] = (v.y - mu) * rstd * gv.y + bv.y;
    o[2] = (v.z - mu) * rstd * gv.z + bv.z;
    o[3] = (v.w - mu) * rstd * gv.w + bv.w;
    u16 h[4], l[4];
#pragma unroll
    for (int i = 0; i < 4; ++i) {
        h[i] = f2bf(o[i]);
        l[i] = f2bf(o[i] - bf2f(h[i]));
    }
    uint2 ph, pl2;
    ph.x = (unsigned)h[0] | ((unsigned)h[1] << 16);
    ph.y = (unsigned)h[2] | ((unsigned)h[3] << 16);
    pl2.x = (unsigned)l[0] | ((unsigned)l[1] << 16);
    pl2.y = (unsigned)l[2] | ((unsigned)l[3] << 16);
    *(uint2*)(nh + (size_t)row * DDIM + tid * 4) = ph;
    *(uint2*)(nl + (size_t)row * DDIM + tid * 4) = pl2;
}

// ---------------- transpose + bf16 hi/lo convert: in[R][C] f32 -> out[C][R] ----------------
__global__ __launch_bounds__(256) void transcvt(const float* __restrict__ in,
                                                u16* __restrict__ oh,
                                                u16* __restrict__ ol,
                                                int R, int C)
{
    __shared__ float t[32][33];
    int bx = blockIdx.x, by = blockIdx.y;
    int tx = threadIdx.x & 31, ty = threadIdx.x >> 5;
#pragma unroll
    for (int j = 0; j < 4; ++j)
        t[ty + j * 8][tx] = in[(size_t)(by * 32 + ty + j * 8) * C + bx * 32 + tx];
    __syncthreads();
#pragma unroll
    for (int j = 0; j < 4; ++j) {
        float v = t[tx][ty + j * 8];
        u16 h = f2bf(v);
        size_t o = (size_t)(bx * 32 + ty + j * 8) * R + by * 32 + tx;
        oh[o] = h;
        ol[o] = f2bf(v - bf2f(h));
    }
}

// ---------------- split-bf16 MFMA GEMM (NT): C[z] = A[z] @ Bt[z]^T ----------------
template<int OMODE>
__global__ __launch_bounds__(256) void gemm_mfma(
    const u16* __restrict__ Ah, const u16* __restrict__ Al, long sAz,
    const u16* __restrict__ Bth, const u16* __restrict__ Btl, long sBz,
    float* __restrict__ C, u16* __restrict__ Oh, u16* __restrict__ Ol, long sCz,
    int M, int N, int K,
    const int* __restrict__ pl_ptr, const float* __restrict__ gate_ptr)
{
    int z = blockIdx.z;
    int m0 = blockIdx.y * 128, n0 = blockIdx.x * 128;
    if (pl_ptr) {
        int p = clamp_pl(pl_ptr[0]);
        if (m0 >= (p < M ? p : M)) return;
    }
    Ah  += (size_t)z * sAz;  Al  += (size_t)z * sAz;
    Bth += (size_t)z * sBz;  Btl += (size_t)z * sBz;

    __shared__ u16 As[2][128][32];
    __shared__ u16 Bs[2][128][32];

    int tid = threadIdx.x;
    int wid = tid >> 6, ln = tid & 63;
    int wm = (wid >> 1) * 64, wn = (wid & 1) * 64;
    int r16 = ln & 15, kg = ln >> 4;

    int rb = wid * 32;
    int lr = ln >> 2;
    int sl = ln & 3;
    int koff = (sl ^ (((rb + lr) >> 1) & 3)) * 8;

    const u16* gA0h = Ah  + (size_t)(m0 + rb + lr) * K + koff;
    const u16* gA1h = gA0h + (size_t)16 * K;
    const u16* gA0l = Al  + (size_t)(m0 + rb + lr) * K + koff;
    const u16* gA1l = gA0l + (size_t)16 * K;
    const u16* gB0h = Bth + (size_t)(n0 + rb + lr) * K + koff;
    const u16* gB1h = gB0h + (size_t)16 * K;
    const u16* gB0l = Btl + (size_t)(n0 + rb + lr) * K + koff;
    const u16* gB1l = gB0l + (size_t)16 * K;

    u16* lA0h = &As[0][rb][0];      u16* lA1h = &As[0][rb + 16][0];
    u16* lA0l = &As[1][rb][0];      u16* lA1l = &As[1][rb + 16][0];
    u16* lB0h = &Bs[0][rb][0];      u16* lB1h = &Bs[0][rb + 16][0];
    u16* lB0l = &Bs[1][rb][0];      u16* lB1l = &Bs[1][rb + 16][0];

    f32x4 acc[4][4];
#pragma unroll
    for (int mt = 0; mt < 4; ++mt)
#pragma unroll
        for (int nt = 0; nt < 4; ++nt)
            acc[mt][nt] = (f32x4){0.f, 0.f, 0.f, 0.f};

    for (int k0 = 0; k0 < K; k0 += 32) {
        __syncthreads();
        gload16(gA0h, lA0h);  gload16(gA1h, lA1h);
        gload16(gA0l, lA0l);  gload16(gA1l, lA1l);
        gload16(gB0h, lB0h);  gload16(gB1h, lB1h);
        gload16(gB0l, lB0l);  gload16(gB1l, lB1l);
        gA0h += 32; gA1h += 32; gA0l += 32; gA1l += 32;
        gB0h += 32; gB1h += 32; gB0l += 32; gB1l += 32;
        __syncthreads();

        bf16x8 bhf[4], blf[4];
#pragma unroll
        for (int nt = 0; nt < 4; ++nt) {
            int r = wn + nt * 16 + r16;
            int s = (kg ^ ((r >> 1) & 3)) * 8;
            bhf[nt] = *(const bf16x8*)&Bs[0][r][s];
            blf[nt] = *(const bf16x8*)&Bs[1][r][s];
        }
#pragma unroll
        for (int mt = 0; mt < 4; ++mt) {
            int r = wm + mt * 16 + r16;
            int s = (kg ^ ((r >> 1) & 3)) * 8;
            bf16x8 ah = *(const bf16x8*)&As[0][r][s];
            bf16x8 al = *(const bf16x8*)&As[1][r][s];
#pragma unroll
            for (int nt = 0; nt < 4; ++nt) {
                acc[mt][nt] = __builtin_amdgcn_mfma_f32_16x16x32_bf16(ah, bhf[nt], acc[mt][nt], 0, 0, 0);
                acc[mt][nt] = __builtin_amdgcn_mfma_f32_16x16x32_bf16(ah, blf[nt], acc[mt][nt], 0, 0, 0);
                acc[mt][nt] = __builtin_amdgcn_mfma_f32_16x16x32_bf16(al, bhf[nt], acc[mt][nt], 0, 0, 0);
            }
        }
    }

    int orow0 = m0 + wm + kg * 4;
    int ocol0 = n0 + wn + r16;
    if (OMODE == 0) {
        float scale = 1.0f;
        if (gate_ptr) scale = 1.0f / (1.0f + expf(-gate_ptr[0]));
        float* Cz = C + (size_t)z * sCz;
#pragma unroll
        for (int mt = 0; mt < 4; ++mt)
#pragma unroll
            for (int nt = 0; nt < 4; ++nt)
#pragma unroll
                for (int j = 0; j < 4; ++j)
                    Cz[(size_t)(orow0 + mt * 16 + j) * N + ocol0 + nt * 16] = acc[mt][nt][j] * scale;
    } else {
        u16* Ohz = Oh + (size_t)z * sCz;
        u16* Olz = Ol + (size_t)z * sCz;
#pragma unroll
        for (int mt = 0; mt < 4; ++mt)
#pragma unroll
            for (int nt = 0; nt < 4; ++nt)
#pragma unroll
                for (int j = 0; j < 4; ++j) {
                    float v = acc[mt][nt][j];
                    u16 h = f2bf(v);
                    size_t o = (size_t)(orow0 + mt * 16 + j) * N + ocol0 + nt * 16;
                    Ohz[o] = h;
                    Olz[o] = f2bf(v - bf2f(h));
                }
    }
}

// ---------------- Gram statistics, 16-way INTERLEAVED time-split partials ----------------
// Block sp handles 64-row chunks c0 = sp*64, sp*64+1024, ... (stride GSPLIT*64).
// For pl=1024 all 1024 blocks get exactly one chunk (balanced, no zero-writers).
__global__ __launch_bounds__(256) void gram_kernel(const float* __restrict__ Kp,
                                                   const float* __restrict__ Vp,
                                                   float* __restrict__ Gpart,
                                                   float* __restrict__ Mpart,
                                                   float* __restrict__ Cpart,
                                                   const int* __restrict__ pl_ptr)
{
    int h = blockIdx.x, b = blockIdx.y, sp = blockIdx.z;
    int pl = clamp_pl(pl_ptr[0]);
    __shared__ float pks[65][48];
    __shared__ float pvs[64][64];
    int tid = threadIdx.x;
    int tx = tid & 15, ty = tid >> 4;
    float gacc[3][3] = {}, macc[3][3] = {}, cacc[4][3] = {};
    const float* Kbase = Kp + (size_t)b * TLEN * HR + h * RDIM;
    const float* Vbase = Vp + (size_t)b * TLEN * HHD + h * HDIM;
    const float4 z4 = make_float4(0.f, 0.f, 0.f, 0.f);

    for (int c0 = sp * 64; c0 < pl; c0 += GSPLIT * 64) {
        for (int idx = tid; idx < 65 * 12; idx += 256) {
            int rr = idx / 12, c4 = idx % 12;
            int tg = c0 + rr;
            *(float4*)&pks[rr][c4 * 4] =
                (tg < pl) ? *(const float4*)&Kbase[(size_t)tg * HR + c4 * 4] : z4;
        }
        for (int idx = tid; idx < 64 * 16; idx += 256) {
            int rr = idx >> 4, c4 = idx & 15;
            int tg = c0 + rr;
            *(float4*)&pvs[rr][c4 * 4] =
                (tg < pl) ? *(const float4*)&Vbase[(size_t)tg * HHD + c4 * 4] : z4;
        }
        __syncthreads();
#pragma unroll 2
        for (int l = 0; l < 64; ++l) {
            float a0[3], a1[3], bb[3], vv[4];
#pragma unroll
            for (int i = 0; i < 3; ++i) {
                a0[i] = pks[l][tx * 3 + i];
                a1[i] = pks[l + 1][tx * 3 + i];
                bb[i] = pks[l][ty * 3 + i];
            }
#pragma unroll
            for (int j = 0; j < 4; ++j) vv[j] = pvs[l][ty * 4 + j];
#pragma unroll
            for (int i = 0; i < 3; ++i)
#pragma unroll
                for (int j = 0; j < 3; ++j) {
                    gacc[i][j] += a0[i] * bb[j];
                    macc[i][j] += a1[i] * bb[j];
                }
#pragma unroll
            for (int j = 0; j < 4; ++j)
#pragma unroll
                for (int i = 0; i < 3; ++i)
                    cacc[j][i] += vv[j] * a0[i];
        }
        __syncthreads();
    }
    size_t pbase = (size_t)sp * (BSZ * NH) + b * NH + h;
    float* Gp = Gpart + pbase * 2304;
    float* Mp = Mpart + pbase * 2304;
    float* Cp = Cpart + pbase * 3072;
#pragma unroll
    for (int i = 0; i < 3; ++i)
#pragma unroll
        for (int j = 0; j < 3; ++j) {
            Gp[(tx * 3 + i) * 48 + (ty * 3 + j)] = gacc[i][j];
            Mp[(tx * 3 + i) * 48 + (ty * 3 + j)] = macc[i][j];
        }
#pragma unroll
    for (int j = 0; j < 4; ++j)
#pragma unroll
        for (int i = 0; i < 3; ++i)
            Cp[(ty * 4 + j) * 48 + (tx * 3 + i)] = cacc[j][i];
}

// reduce GSPLIT partials into the per-k slot of Gb/Mb/Cb
__global__ __launch_bounds__(256) void gram_reduce(const float* __restrict__ Gpart,
                                                   const float* __restrict__ Mpart,
                                                   const float* __restrict__ Cpart,
                                                   float* __restrict__ Gb,
                                                   float* __restrict__ Mb,
                                                   float* __restrict__ Cb,
                                                   int k)
{
    int p = blockIdx.x;               // b*NH+h
    size_t ob = ((size_t)k * (BSZ * NH) + p);
    for (int idx = threadIdx.x; idx < 2304; idx += 256) {
        float sg = 0.f, sm = 0.f;
#pragma unroll
        for (int sp = 0; sp < GSPLIT; ++sp) {
            size_t pb = ((size_t)sp * (BSZ * NH) + p);
            sg += Gpart[pb * 2304 + idx];
            sm += Mpart[pb * 2304 + idx];
        }
        Gb[ob * 2304 + idx] = sg;
        Mb[ob * 2304 + idx] = sm;
    }
    for (int idx = threadIdx.x; idx < 3072; idx += 256) {
        float sc = 0.f;
#pragma unroll
        for (int sp = 0; sp < GSPLIT; ++sp)
            sc += Cpart[((size_t)sp * (BSZ * NH) + p) * 3072 + idx];
        Cb[ob * 3072 + idx] = sc;
    }
}

// ---------------- per-(k,b,h) solver stage 1: W = scl^2 * P*P*H ----------------
// H = (G+ridge I)^{-1} via Gauss-Jordan: 1 barrier/pivot, triangular column ranges.
// P = H*M; R = H*M^T; Q = R*P; Q2 = Q*Q; sigma^4 = lambda_max(Q2) by power
// iteration (48 iters == 96 on Q); X = P*H; W = s2*P*X (transposed out).
__global__ __launch_bounds__(256) void solver_kernel(const float* __restrict__ Gb,
                                                     const float* __restrict__ Mb,
                                                     float* __restrict__ Wg,
                                                     const float* __restrict__ log_ridges,
                                                     const float* __restrict__ log_gammas)
{
    int blk = blockIdx.x;                 // (k*BSZ + b)*NH + h
    int k = blk / (BSZ * NH);
    int tid = threadIdx.x;
    int ti = tid >> 4, tj = tid & 15;
    int i0 = ti * 3, j0 = tj * 3;

    __shared__ float A [48 * SST];        // G -> GJ(D) -> M^T -> R -> Q^T -> X^T
    __shared__ float Hs[48 * SST];        // I -> B -> H = G^{-1}
    __shared__ float Mm[48 * SST];        // M -> Q
    __shared__ float Pm[48 * SST];        // P  (row-major)
    __shared__ float Pt[48 * SST];        // P^T -> Q2
    __shared__ float pvb[4][SST];

    size_t base = (size_t)blk;
    const float* Gp = Gb + base * 2304;
    const float* Mp = Mb + base * 2304;
    float ridge = expf(log_ridges[k]);

    for (int idx = tid; idx < 2304; idx += 256) {
        int i = idx / 48, j = idx % 48;
        A [i * SST + j] = Gp[idx] + ((i == j) ? ridge : 0.f);
        Hs[i * SST + j] = (i == j) ? 1.f : 0.f;
        Mm[i * SST + j] = Mp[idx];
    }
    __syncthreads();

    // ---- Gauss-Jordan, deferred row-scaling, 1 barrier/pivot, triangular ranges ----
    for (int p = 0; p < 48; ++p) {
        int p4 = p >> 2;
        float pr = 1.0f / fmaxf(A[p * SST + p], 1e-30f);   // SPD -> pivot > 0
        int c4a = p4 + 1;              // first full A float4 col-block (> p)
        int nA4 = 11 - p4;             // A blocks [c4a..11]
        int nb  = 3 - (p & 3);         // boundary scalar cols (p+1 .. 4*c4a-1)
        for (int q = tid; q < 576; q += 256) {   // 48 rows x 12 float4 blocks
            int i = q / 12, c = q % 12;
            if (i == p) continue;
            float f = A[i * SST + p] * pr;
            if (c < nA4) {
                int c4 = c4a + c;
                float4 prw = *(const float4*)&A[p * SST + c4 * 4];
                float4* d = (float4*)&A[i * SST + c4 * 4];
                float4 v = *d;
                v.x -= f * prw.x; v.y -= f * prw.y;
                v.z -= f * prw.z; v.w -= f * prw.w;
                *d = v;
            } else {
                int c4 = c - nA4;      // 0 .. p4  (Hs cols <= p; extras are f*0)
                float4 prw = *(const float4*)&Hs[p * SST + c4 * 4];
                float4* d = (float4*)&Hs[i * SST + c4 * 4];
                float4 v = *d;
                v.x -= f * prw.x; v.y -= f * prw.y;
                v.z -= f * prw.z; v.w -= f * prw.w;
                *d = v;
            }
        }
        if (nb) {
            for (int i = tid; i < 48; i += 256) {
                if (i == p) continue;
                float f = A[i * SST + p] * pr;
                for (int c = p + 1; c < 4 * c4a; ++c)
                    A[i * SST + c] -= f * A[p * SST + c];
            }
        }
        __syncthreads();
    }
    // H = D^{-1} B  (row-wise scale by 1/d_i, d_i = A[i][i])
    for (int idx = tid; idx < 2304; idx += 256) {
        int i = idx / 48, j = idx % 48;
        Hs[i * SST + j] /= fmaxf(A[i * SST + i], 1e-30f);
    }
    __syncthreads();
    // ---- M^T into A (GJ remnants dead) ----
    for (int idx = tid; idx < 2304; idx += 256) {
        int i = idx / 48, j = idx % 48;
        A[j * SST + i] = Mm[i * SST + j];
    }
    __syncthreads();
    // ---- P = H*M: tile = dot(Hs rows, Mt=A rows); store Pm and Pt ----
    {
        float acc[3][3];
        mm48_3x3(Hs, A, i0, j0, acc);
#pragma unroll
        for (int r = 0; r < 3; ++r)
#pragma unroll
            for (int c = 0; c < 3; ++c) {
                Pm[(i0 + r) * SST + j0 + c] = acc[r][c];
                Pt[(j0 + c) * SST + i0 + r] = acc[r][c];
            }
    }
    __syncthreads();
    // ---- R = H*M^T into A (Mt dead): dot(Hs rows, Mm rows) ----
    {
        float acc[3][3];
        mm48_3x3(Hs, Mm, i0, j0, acc);
        __syncthreads();                      // Mt reads done before overwriting A
#pragma unroll
        for (int r = 0; r < 3; ++r)
#pragma unroll
            for (int c = 0; c < 3; ++c)
                A[(i0 + r) * SST + j0 + c] = acc[r][c];
    }
    __syncthreads();
    // ---- Q = R*P: dot(A rows, Pt rows) -> Q into Mm (M dead), Q^T into A ----
    {
        float acc[3][3];
        mm48_3x3(A, Pt, i0, j0, acc);
        __syncthreads();                      // R/Pt reads done before overwrite
#pragma unroll
        for (int r = 0; r < 3; ++r)
#pragma unroll
            for (int c = 0; c < 3; ++c) {
                Mm[(i0 + r) * SST + j0 + c] = acc[r][c];
                A [(j0 + c) * SST + i0 + r] = acc[r][c];
            }
    }
    __syncthreads();
    // ---- Q2 = Q*Q: Q2[i][j] = dot(Q[i], Qt[j]) = dot(Mm[i], A[j]) -> into Pt (dead) ----
    {
        float acc[3][3];
        mm48_3x3(Mm, A, i0, j0, acc);
#pragma unroll
        for (int r = 0; r < 3; ++r)
#pragma unroll
            for (int c = 0; c < 3; ++c)
                Pt[(i0 + r) * SST + j0 + c] = acc[r][c];
    }
    __syncthreads();

    // ---- power iteration on Q2 (48 iters == 96 on Q): redundant per wave ----
    int ln = tid & 63, w = tid >> 6;
    float* pv = pvb[w];
    if (ln < 48) pv[ln] = ((float)((ln * 2654435761u) & 0xFFFF)) / 65536.0f + 0.5f;
    WB();
    float lam = 0.f;
    for (int it = 0; it < 49; ++it) {
        float z = 0.f;
        if (ln < 48) z = dot48(&Pt[ln * SST], pv);
        if (it == 48) {
            float nn = z * z;
            for (int off = 1; off < 64; off <<= 1) nn += __shfl_xor(nn, off);
            lam = sqrtf(nn);               // lambda_max(Q2) = sigma_max^4
            break;
        }
        if ((it & 3) == 3) {
            float nn = z * z;
            for (int off = 1; off < 64; off <<= 1) nn += __shfl_xor(nn, off);
            z *= rsqrtf(fmaxf(nn, 1e-30f));
        }
        WB();
        if (ln < 48) pv[ln] = z;
        WB();
    }
    float sigma = sqrtf(sqrtf(fmaxf(lam, 0.f)));
    float gamma = expf(log_gammas[k]);
    float scl = fminf(gamma, 1.f) / fmaxf(fmaxf(sigma, 1e-8f), 1.f);
    float s2 = scl * scl;

    // ---- X^T into A (Qt dead; all waves past the post-Q2 barrier):
    //      X = P*H, H symmetric -> X[i][j] = dot(Pm[i], Hs[j]) ----
    {
        float acc[3][3];
        mm48_3x3(Pm, Hs, i0, j0, acc);
        __syncthreads();                      // power-phase Pt/A reads done
#pragma unroll
        for (int r = 0; r < 3; ++r)
#pragma unroll
            for (int c = 0; c < 3; ++c)
                A[(j0 + c) * SST + i0 + r] = acc[r][c];
    }
    __syncthreads();
    // ---- W = s2*P*X: dot(Pm rows, Xt=A rows); store transposed to global ----
    {
        float acc[3][3];
        mm48_3x3(Pm, A, i0, j0, acc);
#pragma unroll
        for (int r = 0; r < 3; ++r)
#pragma unroll
            for (int c = 0; c < 3; ++c)
                Wg[base * 2304 + (size_t)(j0 + c) * 48 + i0 + r] = s2 * acc[r][c];
    }
}

// ---------------- solver stage 2: F = C_v * W  (64x48 = [64x48][48x48]) ----------------
// register-tiled 4x3 per thread.
__global__ __launch_bounds__(256) void solver2_kernel(const float* __restrict__ Cb,
                                                      const float* __restrict__ Wg,
                                                      float* __restrict__ Fb)
{
    int blk = blockIdx.x;
    int tid = threadIdx.x;
    int ti = tid >> 4, tj = tid & 15;
    int i0 = ti * 4, j0 = tj * 3;
    __shared__ float CvL[64 * SST];
    __shared__ float WtL[48 * SST];       // row j = W[.][j]
    const float* Cp = Cb + (size_t)blk * 3072;
    const float* Wp = Wg + (size_t)blk * 2304;
    for (int idx = tid; idx < 3072; idx += 256)
        CvL[(idx / 48) * SST + (idx % 48)] = Cp[idx];
    for (int idx = tid; idx < 2304; idx += 256)
        WtL[(idx / 48) * SST + (idx % 48)] = Wp[idx];
    __syncthreads();
    float acc[4][3];
#pragma unroll
    for (int r = 0; r < 4; ++r)
#pragma unroll
        for (int c = 0; c < 3; ++c) acc[r][c] = 0.f;
#pragma unroll 4
    for (int m = 0; m < 12; ++m) {
        float4 a0 = *(const float4*)(CvL + (i0 + 0) * SST + m * 4);
        float4 a1 = *(const float4*)(CvL + (i0 + 1) * SST + m * 4);
        float4 a2 = *(const float4*)(CvL + (i0 + 2) * SST + m * 4);
        float4 a3 = *(const float4*)(CvL + (i0 + 3) * SST + m * 4);
        float4 b0 = *(const float4*)(WtL + (j0 + 0) * SST + m * 4);
        float4 b1 = *(const float4*)(WtL + (j0 + 1) * SST + m * 4);
        float4 b2 = *(const float4*)(WtL + (j0 + 2) * SST + m * 4);
        acc[0][0] += a0.x*b0.x + a0.y*b0.y + a0.z*b0.z + a0.w*b0.w;
        acc[0][1] += a0.x*b1.x + a0.y*b1.y + a0.z*b1.z + a0.w*b1.w;
        acc[0][2] += a0.x*b2.x + a0.y*b2.y + a0.z*b2.z + a0.w*b2.w;
        acc[1][0] += a1.x*b0.x + a1.y*b0.y + a1.z*b0.z + a1.w*b0.w;
        acc[1][1] += a1.x*b1.x + a1.y*b1.y + a1.z*b1.z + a1.w*b1.w;
        acc[1][2] += a1.x*b2.x + a1.y*b2.y + a1.z*b2.z + a1.w*b2.w;
        acc[2][0] += a2.x*b0.x + a2.y*b0.y + a2.z*b0.z + a2.w*b0.w;
        acc[2][1] += a2.x*b1.x + a2.y*b1.y + a2.z*b1.z + a2.w*b1.w;
        acc[2][2] += a2.x*b2.x + a2.y*b2.y + a2.z*b2.z + a2.w*b2.w;
        acc[3][0] += a3.x*b0.x + a3.y*b0.y + a3.z*b0.z + a3.w*b0.w;
        acc[3][1] += a3.x*b1.x + a3.y*b1.y + a3.z*b1.z + a3.w*b1.w;
        acc[3][2] += a3.x*b2.x + a3.y*b2.y + a3.z*b2.z + a3.w*b2.w;
    }
#pragma unroll
    for (int r = 0; r < 4; ++r)
#pragma unroll
        for (int c = 0; c < 3; ++c)
            Fb[(size_t)blk * 3072 + (size_t)(i0 + r) * 48 + j0 + c] = acc[r][c];
}

// ---------------- W_cmb build -> bf16 hi/lo ----------------
__global__ __launch_bounds__(256) void wcmb_kernel(const float* __restrict__ WQ,
                                                   const float* __restrict__ Fb,
                                                   const float* __restrict__ gate_alphas,
                                                   u16* __restrict__ Wh,
                                                   u16* __restrict__ Wl)
{
    int dt = blockIdx.x;  // row tile (0..15)
    int h = blockIdx.y, b = blockIdx.z;
    __shared__ float wq[64][49];
    __shared__ float fs[64][49];
    int tid = threadIdx.x;
    int tx = tid & 15, ty = tid >> 4;
    float acc[4][4] = {};
    for (int k = 0; k < NKOPS; ++k) {
        float gate = 1.0f / (1.0f + expf(-gate_alphas[k]));
        for (int idx = tid; idx < 64 * 48; idx += 256) {
            int rr = idx / 48, cc = idx % 48;
            wq[rr][cc] = WQ[((size_t)k * DDIM + dt * 64 + rr) * HR + h * RDIM + cc];
            fs[rr][cc] = gate * Fb[(((size_t)k * BSZ + b) * NH + h) * 3072 + idx];
        }
        __syncthreads();
        for (int r = 0; r < 48; ++r) {
            float a[4], bb[4];
#pragma unroll
            for (int i = 0; i < 4; ++i) { a[i] = wq[tx * 4 + i][r]; bb[i] = fs[ty * 4 + i][r]; }
#pragma unroll
            for (int i = 0; i < 4; ++i)
#pragma unroll
                for (int j = 0; j < 4; ++j)
                    acc[i][j] += a[i] * bb[j];
        }
        __syncthreads();
    }
#pragma unroll
    for (int i = 0; i < 4; ++i)
#pragma unroll
        for (int j = 0; j < 4; ++j) {
            size_t o = ((size_t)b * DDIM + dt * 64 + tx * 4 + i) * HHD + h * HDIM + ty * 4 + j;
            float v = acc[i][j];
            u16 hh = f2bf(v);
            Wh[o] = hh;
            Wl[o] = f2bf(v - bf2f(hh));
        }
}

// ---------------- host launch ----------------
extern "C" void kernel_launch(void* const* d_in, const int* in_sizes, int n_in,
                              void* d_out, int out_size, void* d_ws, size_t ws_size,
                              hipStream_t stream)
{
    const float* hs          = (const float*)d_in[0];
    const float* WK          = (const float*)d_in[1];
    const float* WQ          = (const float*)d_in[2];
    const float* WV          = (const float*)d_in[3];
    const float* WO          = (const float*)d_in[4];
    const float* ln_g        = (const float*)d_in[5];
    const float* ln_b        = (const float*)d_in[6];
    const float* gate_alphas = (const float*)d_in[7];
    const float* gate_alpha  = (const float*)d_in[8];
    const float* log_ridges  = (const float*)d_in[9];
    const float* log_gammas  = (const float*)d_in[10];
    const int*   pl_ptr      = (const int*)d_in[11];
    float* out = (float*)d_out;

    float* wsf = (float*)d_ws;
    u16* n_hi   = (u16*)(wsf + 0);          // 8,388,608 u16
    u16* n_lo   = (u16*)(wsf + 4194304);
    u16* WVt_h  = (u16*)(wsf + 8388608);    // 1,048,576 u16
    u16* WVt_l  = (u16*)(wsf + 8912896);
    u16* WKt_h  = (u16*)(wsf + 9437184);    // 786,432 u16
    u16* WKt_l  = (u16*)(wsf + 9830400);
    float* Vp   = wsf + 10223616;           // 8,388,608 f32
    float* Kp   = wsf + 18612224;           // 6,291,456 f32
    float* Gb   = wsf + 24903680;           // 589,824
    float* Mb   = wsf + 25493504;           // 589,824
    float* Cb   = wsf + 26083328;           // 786,432  (end: 26,869,760 f = 102.5 MiB)
    // aliases (lifetimes disjoint, stream-ordered)
    u16* Wcmb_h  = (u16*)Vp;                // after grams
    u16* Wcmb_l  = (u16*)(Vp + 2097152);
    u16* Wfint_h = (u16*)(Vp + 4194304);
    u16* Wfint_l = (u16*)(Vp + 6291456);
    u16* WOt_h   = (u16*)Kp;                // after grams
    u16* WOt_l   = (u16*)(Kp + 524288);
    float* Fb    = Kp + 1048576;            // 786,432
    float* Wg    = Kp + 1835008;            // 589,824 (all within Kp region)
    // gram partials live in d_out (dead before final GEMM overwrites all of d_out)
    float* Gpart = out;                     // 16*64*2304 = 2,359,296
    float* Mpart = out + 2359296;           // 2,359,296
    float* Cpart = out + 4718592;           // 16*64*3072 = 3,145,728 (end 7,864,320 < 8,388,608)

    ln_kernel<<<BSZ * TLEN, 256, 0, stream>>>(hs, ln_g, ln_b, n_hi, n_lo);

    // WVt = WV^T (hi/lo);  Vp = normed_prefix @ WV
    transcvt<<<dim3(HHD / 32, DDIM / 32), 256, 0, stream>>>(WV, WVt_h, WVt_l, DDIM, HHD);
    gemm_mfma<0><<<dim3(HHD / 128, TLEN / 128, BSZ), 256, 0, stream>>>(
        n_hi, n_lo, (long)TLEN * DDIM, WVt_h, WVt_l, 0,
        Vp, nullptr, nullptr, (long)TLEN * HHD,
        TLEN, HHD, DDIM, pl_ptr, nullptr);

    for (int k = 0; k < NKOPS; ++k) {
        transcvt<<<dim3(HR / 32, DDIM / 32), 256, 0, stream>>>(
            WK + (size_t)k * DDIM * HR, WKt_h, WKt_l, DDIM, HR);
        gemm_mfma<0><<<dim3(HR / 128, TLEN / 128, BSZ), 256, 0, stream>>>(
            n_hi, n_lo, (long)TLEN * DDIM, WKt_h, WKt_l, 0,
            Kp, nullptr, nullptr, (long)TLEN * HR,
            TLEN, HR, DDIM, pl_ptr, nullptr);
        gram_kernel<<<dim3(NH, BSZ, GSPLIT), 256, 0, stream>>>(Kp, Vp, Gpart, Mpart, Cpart, pl_ptr);
        gram_reduce<<<BSZ * NH, 256, 0, stream>>>(Gpart, Mpart, Cpart, Gb, Mb, Cb, k);
    }

    // WOt = WO^T (into Kp region, now dead)
    transcvt<<<dim3(DDIM / 32, HHD / 32), 256, 0, stream>>>(WO, WOt_h, WOt_l, HHD, DDIM);

    solver_kernel<<<NKOPS * BSZ * NH, 256, 0, stream>>>(Gb, Mb, Wg, log_ridges, log_gammas);
    solver2_kernel<<<NKOPS * BSZ * NH, 256, 0, stream>>>(Cb, Wg, Fb);

    wcmb_kernel<<<dim3(DDIM / 64, NH, BSZ), 256, 0, stream>>>(WQ, Fb, gate_alphas, Wcmb_h, Wcmb_l);

    // Wfint[b] = WO^T @ Wcmb[b]^T  == Wfin[b]^T, written bf16 hi/lo row-major
    gemm_mfma<1><<<dim3(DDIM / 128, DDIM / 128, BSZ), 256, 0, stream>>>(
        WOt_h, WOt_l, 0, Wcmb_h, Wcmb_l, (long)DDIM * HHD,
        nullptr, Wfint_h, Wfint_l, (long)DDIM * DDIM,
        DDIM, DDIM, HHD, nullptr, nullptr);

    // out[b] = sigmoid(gate_alpha) * normed[b] @ Wfin[b]
    gemm_mfma<0><<<dim3(DDIM / 128, TLEN / 128, BSZ), 256, 0, stream>>>(
        n_hi, n_lo, (long)TLEN * DDIM, Wfint_h, Wfint_l, (long)DDIM * DDIM,
        out, nullptr, nullptr, (long)TLEN * DDIM,
        TLEN, DDIM, DDIM, nullptr, gate_alpha);
}

// Round 15
// 640.346 us; speedup vs baseline: 1.1945x; 1.0113x over previous
//
#include <hip/hip_runtime.h>
#include <math.h>

typedef unsigned short u16;
typedef __attribute__((ext_vector_type(8))) short bf16x8;
typedef __attribute__((ext_vector_type(4))) float f32x4;

#define BSZ 4
#define TLEN 2048
#define DDIM 1024
#define NH 16
#define HDIM 64
#define NKOPS 4
#define RDIM 48
#define HR 768     // NH*RDIM
#define HHD 1024   // NH*HDIM
#define LNEPS 1e-5f
#define GSPLIT 16
#define SST 52     // solver LDS row stride (208 B, 16B-aligned)

#define AS1 __attribute__((address_space(1)))
#define AS3 __attribute__((address_space(3)))

static __device__ __forceinline__ void gload16(const u16* g, u16* l) {
    __builtin_amdgcn_global_load_lds((const AS1 unsigned int*)g, (AS3 unsigned int*)l, 16, 0, 0);
}

static __device__ __forceinline__ int clamp_pl(int p) {
    if (p < 1) p = 1;
    if (p > TLEN - 1) p = TLEN - 1;
    return p;
}

static __device__ __forceinline__ u16 f2bf(float x) {
    unsigned u = __float_as_uint(x);
    return (u16)((u + 0x7FFFu + ((u >> 16) & 1u)) >> 16);
}
static __device__ __forceinline__ float bf2f(u16 h) {
    return __uint_as_float(((unsigned)h) << 16);
}

// 48-elem dot of two 16B-aligned LDS rows via 12+12 ds_read_b128
static __device__ __forceinline__ float dot48(const float* __restrict__ a,
                                              const float* __restrict__ b) {
    float s0 = 0.f, s1 = 0.f, s2 = 0.f, s3 = 0.f;
#pragma unroll
    for (int m = 0; m < 12; ++m) {
        float4 av = *(const float4*)(a + m * 4);
        float4 bv = *(const float4*)(b + m * 4);
        s0 += av.x * bv.x; s1 += av.y * bv.y;
        s2 += av.z * bv.z; s3 += av.w * bv.w;
    }
    return (s0 + s1) + (s2 + s3);
}

// register-tiled 3x3 block of a 48x48 row.row matmul:
// acc[r][c] = dot(L[i0+r], R[j0+c]), rows 16B-aligned stride SST.
static __device__ __forceinline__ void mm48_3x3(const float* __restrict__ Lb,
                                                const float* __restrict__ Rb,
                                                int i0, int j0, float acc[3][3]) {
#pragma unroll
    for (int r = 0; r < 3; ++r)
#pragma unroll
        for (int c = 0; c < 3; ++c) acc[r][c] = 0.f;
#pragma unroll 4
    for (int m = 0; m < 12; ++m) {
        float4 a0 = *(const float4*)(Lb + (i0 + 0) * SST + m * 4);
        float4 a1 = *(const float4*)(Lb + (i0 + 1) * SST + m * 4);
        float4 a2 = *(const float4*)(Lb + (i0 + 2) * SST + m * 4);
        float4 b0 = *(const float4*)(Rb + (j0 + 0) * SST + m * 4);
        float4 b1 = *(const float4*)(Rb + (j0 + 1) * SST + m * 4);
        float4 b2 = *(const float4*)(Rb + (j0 + 2) * SST + m * 4);
        acc[0][0] += a0.x * b0.x + a0.y * b0.y + a0.z * b0.z + a0.w * b0.w;
        acc[0][1] += a0.x * b1.x + a0.y * b1.y + a0.z * b1.z + a0.w * b1.w;
        acc[0][2] += a0.x * b2.x + a0.y * b2.y + a0.z * b2.z + a0.w * b2.w;
        acc[1][0] += a1.x * b0.x + a1.y * b0.y + a1.z * b0.z + a1.w * b0.w;
        acc[1][1] += a1.x * b1.x + a1.y * b1.y + a1.z * b1.z + a1.w * b1.w;
        acc[1][2] += a1.x * b2.x + a1.y * b2.y + a1.z * b2.z + a1.w * b2.w;
        acc[2][0] += a2.x * b0.x + a2.y * b0.y + a2.z * b0.z + a2.w * b0.w;
        acc[2][1] += a2.x * b1.x + a2.y * b1.y + a2.z * b1.z + a2.w * b1.w;
        acc[2][2] += a2.x * b2.x + a2.y * b2.y + a2.z * b2.z + a2.w * b2.w;
    }
}

#define WB() __builtin_amdgcn_wave_barrier()

// ---------------- LayerNorm -> bf16 hi/lo split ----------------
__global__ __launch_bounds__(256) void ln_kernel(const float* __restrict__ hs,
                                                 const float* __restrict__ g,
                                                 const float* __restrict__ b,
                                                 u16* __restrict__ nh,
                                                 u16* __restrict__ nl)
{
    int row = blockIdx.x;
    int tid = threadIdx.x;
    const float* x = hs + (size_t)row * DDIM;
    float4 v = ((const float4*)x)[tid];
    float s  = v.x + v.y + v.z + v.w;
    float ss = v.x*v.x + v.y*v.y + v.z*v.z + v.w*v.w;
    for (int off = 32; off > 0; off >>= 1) {
        s  += __shfl_down(s, off);
        ss += __shfl_down(ss, off);
    }
    __shared__ float rs[4], rss[4], st[2];
    int wid = tid >> 6, lane = tid & 63;
    if (lane == 0) { rs[wid] = s; rss[wid] = ss; }
    __syncthreads();
    if (tid == 0) {
        float S  = rs[0] + rs[1] + rs[2] + rs[3];
        float SS = rss[0] + rss[1] + rss[2] + rss[3];
        float mu = S / (float)DDIM;
        float var = SS / (float)DDIM - mu * mu;
        st[0] = mu;
        st[1] = rsqrtf(var + LNEPS);
    }
    __syncthreads();
    float mu = st[0], rstd = st[1];
    float4 gv = ((const float4*)g)[tid];
    float4 bv = ((const float4*)b)[tid];
    float o[4];
    o[0] = (v.x - mu) * rstd * gv.x + bv.x;
    o[1] = (v.y - mu) * rstd * gv.y + bv.y;
    o[2] = (v.z - mu) * rstd * gv.z + bv.z;
    o[3] = (v.w - mu) * rstd * gv.w + bv.w;
    u16 h[4], l[4];
#pragma unroll
    for (int i = 0; i < 4; ++i) {
        h[i] = f2bf(o[i]);
        l[i] = f2bf(o[i] - bf2f(h[i]));
    }
    uint2 ph, pl2;
    ph.x = (unsigned)h[0] | ((unsigned)h[1] << 16);
    ph.y = (unsigned)h[2] | ((unsigned)h[3] << 16);
    pl2.x = (unsigned)l[0] | ((unsigned)l[1] << 16);
    pl2.y = (unsigned)l[2] | ((unsigned)l[3] << 16);
    *(uint2*)(nh + (size_t)row * DDIM + tid * 4) = ph;
    *(uint2*)(nl + (size_t)row * DDIM + tid * 4) = pl2;
}

// ---------------- transpose + bf16 hi/lo convert: in[R][C] f32 -> out[C][R] ----------------
__global__ __launch_bounds__(256) void transcvt(const float* __restrict__ in,
                                                u16* __restrict__ oh,
                                                u16* __restrict__ ol,
                                                int R, int C)
{
    __shared__ float t[32][33];
    int bx = blockIdx.x, by = blockIdx.y;
    int tx = threadIdx.x & 31, ty = threadIdx.x >> 5;
#pragma unroll
    for (int j = 0; j < 4; ++j)
        t[ty + j * 8][tx] = in[(size_t)(by * 32 + ty + j * 8) * C + bx * 32 + tx];
    __syncthreads();
#pragma unroll
    for (int j = 0; j < 4; ++j) {
        float v = t[tx][ty + j * 8];
        u16 h = f2bf(v);
        size_t o = (size_t)(bx * 32 + ty + j * 8) * R + by * 32 + tx;
        oh[o] = h;
        ol[o] = f2bf(v - bf2f(h));
    }
}

// ---------------- split-bf16 MFMA GEMM (NT): C[z] = A[z] @ Bt[z]^T ----------------
template<int OMODE>
__global__ __launch_bounds__(256) void gemm_mfma(
    const u16* __restrict__ Ah, const u16* __restrict__ Al, long sAz,
    const u16* __restrict__ Bth, const u16* __restrict__ Btl, long sBz,
    float* __restrict__ C, u16* __restrict__ Oh, u16* __restrict__ Ol, long sCz,
    int M, int N, int K,
    const int* __restrict__ pl_ptr, const float* __restrict__ gate_ptr)
{
    int z = blockIdx.z;
    int m0 = blockIdx.y * 128, n0 = blockIdx.x * 128;
    if (pl_ptr) {
        int p = clamp_pl(pl_ptr[0]);
        if (m0 >= (p < M ? p : M)) return;
    }
    Ah  += (size_t)z * sAz;  Al  += (size_t)z * sAz;
    Bth += (size_t)z * sBz;  Btl += (size_t)z * sBz;

    __shared__ u16 As[2][128][32];
    __shared__ u16 Bs[2][128][32];

    int tid = threadIdx.x;
    int wid = tid >> 6, ln = tid & 63;
    int wm = (wid >> 1) * 64, wn = (wid & 1) * 64;
    int r16 = ln & 15, kg = ln >> 4;

    int rb = wid * 32;
    int lr = ln >> 2;
    int sl = ln & 3;
    int koff = (sl ^ (((rb + lr) >> 1) & 3)) * 8;

    const u16* gA0h = Ah  + (size_t)(m0 + rb + lr) * K + koff;
    const u16* gA1h = gA0h + (size_t)16 * K;
    const u16* gA0l = Al  + (size_t)(m0 + rb + lr) * K + koff;
    const u16* gA1l = gA0l + (size_t)16 * K;
    const u16* gB0h = Bth + (size_t)(n0 + rb + lr) * K + koff;
    const u16* gB1h = gB0h + (size_t)16 * K;
    const u16* gB0l = Btl + (size_t)(n0 + rb + lr) * K + koff;
    const u16* gB1l = gB0l + (size_t)16 * K;

    u16* lA0h = &As[0][rb][0];      u16* lA1h = &As[0][rb + 16][0];
    u16* lA0l = &As[1][rb][0];      u16* lA1l = &As[1][rb + 16][0];
    u16* lB0h = &Bs[0][rb][0];      u16* lB1h = &Bs[0][rb + 16][0];
    u16* lB0l = &Bs[1][rb][0];      u16* lB1l = &Bs[1][rb + 16][0];

    f32x4 acc[4][4];
#pragma unroll
    for (int mt = 0; mt < 4; ++mt)
#pragma unroll
        for (int nt = 0; nt < 4; ++nt)
            acc[mt][nt] = (f32x4){0.f, 0.f, 0.f, 0.f};

    for (int k0 = 0; k0 < K; k0 += 32) {
        __syncthreads();
        gload16(gA0h, lA0h);  gload16(gA1h, lA1h);
        gload16(gA0l, lA0l);  gload16(gA1l, lA1l);
        gload16(gB0h, lB0h);  gload16(gB1h, lB1h);
        gload16(gB0l, lB0l);  gload16(gB1l, lB1l);
        gA0h += 32; gA1h += 32; gA0l += 32; gA1l += 32;
        gB0h += 32; gB1h += 32; gB0l += 32; gB1l += 32;
        __syncthreads();

        bf16x8 bhf[4], blf[4];
#pragma unroll
        for (int nt = 0; nt < 4; ++nt) {
            int r = wn + nt * 16 + r16;
            int s = (kg ^ ((r >> 1) & 3)) * 8;
            bhf[nt] = *(const bf16x8*)&Bs[0][r][s];
            blf[nt] = *(const bf16x8*)&Bs[1][r][s];
        }
#pragma unroll
        for (int mt = 0; mt < 4; ++mt) {
            int r = wm + mt * 16 + r16;
            int s = (kg ^ ((r >> 1) & 3)) * 8;
            bf16x8 ah = *(const bf16x8*)&As[0][r][s];
            bf16x8 al = *(const bf16x8*)&As[1][r][s];
#pragma unroll
            for (int nt = 0; nt < 4; ++nt) {
                acc[mt][nt] = __builtin_amdgcn_mfma_f32_16x16x32_bf16(ah, bhf[nt], acc[mt][nt], 0, 0, 0);
                acc[mt][nt] = __builtin_amdgcn_mfma_f32_16x16x32_bf16(ah, blf[nt], acc[mt][nt], 0, 0, 0);
                acc[mt][nt] = __builtin_amdgcn_mfma_f32_16x16x32_bf16(al, bhf[nt], acc[mt][nt], 0, 0, 0);
            }
        }
    }

    int orow0 = m0 + wm + kg * 4;
    int ocol0 = n0 + wn + r16;
    if (OMODE == 0) {
        float scale = 1.0f;
        if (gate_ptr) scale = 1.0f / (1.0f + expf(-gate_ptr[0]));
        float* Cz = C + (size_t)z * sCz;
#pragma unroll
        for (int mt = 0; mt < 4; ++mt)
#pragma unroll
            for (int nt = 0; nt < 4; ++nt)
#pragma unroll
                for (int j = 0; j < 4; ++j)
                    Cz[(size_t)(orow0 + mt * 16 + j) * N + ocol0 + nt * 16] = acc[mt][nt][j] * scale;
    } else {
        u16* Ohz = Oh + (size_t)z * sCz;
        u16* Olz = Ol + (size_t)z * sCz;
#pragma unroll
        for (int mt = 0; mt < 4; ++mt)
#pragma unroll
            for (int nt = 0; nt < 4; ++nt)
#pragma unroll
                for (int j = 0; j < 4; ++j) {
                    float v = acc[mt][nt][j];
                    u16 h = f2bf(v);
                    size_t o = (size_t)(orow0 + mt * 16 + j) * N + ocol0 + nt * 16;
                    Ohz[o] = h;
                    Olz[o] = f2bf(v - bf2f(h));
                }
    }
}

// ---------------- Gram statistics, 16-way INTERLEAVED time-split partials ----------------
__global__ __launch_bounds__(256) void gram_kernel(const float* __restrict__ Kp,
                                                   const float* __restrict__ Vp,
                                                   float* __restrict__ Gpart,
                                                   float* __restrict__ Mpart,
                                                   float* __restrict__ Cpart,
                                                   const int* __restrict__ pl_ptr)
{
    int h = blockIdx.x, b = blockIdx.y, sp = blockIdx.z;
    int pl = clamp_pl(pl_ptr[0]);
    __shared__ float pks[65][48];
    __shared__ float pvs[64][64];
    int tid = threadIdx.x;
    int tx = tid & 15, ty = tid >> 4;
    float gacc[3][3] = {}, macc[3][3] = {}, cacc[4][3] = {};
    const float* Kbase = Kp + (size_t)b * TLEN * HR + h * RDIM;
    const float* Vbase = Vp + (size_t)b * TLEN * HHD + h * HDIM;
    const float4 z4 = make_float4(0.f, 0.f, 0.f, 0.f);

    for (int c0 = sp * 64; c0 < pl; c0 += GSPLIT * 64) {
        for (int idx = tid; idx < 65 * 12; idx += 256) {
            int rr = idx / 12, c4 = idx % 12;
            int tg = c0 + rr;
            *(float4*)&pks[rr][c4 * 4] =
                (tg < pl) ? *(const float4*)&Kbase[(size_t)tg * HR + c4 * 4] : z4;
        }
        for (int idx = tid; idx < 64 * 16; idx += 256) {
            int rr = idx >> 4, c4 = idx & 15;
            int tg = c0 + rr;
            *(float4*)&pvs[rr][c4 * 4] =
                (tg < pl) ? *(const float4*)&Vbase[(size_t)tg * HHD + c4 * 4] : z4;
        }
        __syncthreads();
#pragma unroll 2
        for (int l = 0; l < 64; ++l) {
            float a0[3], a1[3], bb[3], vv[4];
#pragma unroll
            for (int i = 0; i < 3; ++i) {
                a0[i] = pks[l][tx * 3 + i];
                a1[i] = pks[l + 1][tx * 3 + i];
                bb[i] = pks[l][ty * 3 + i];
            }
#pragma unroll
            for (int j = 0; j < 4; ++j) vv[j] = pvs[l][ty * 4 + j];
#pragma unroll
            for (int i = 0; i < 3; ++i)
#pragma unroll
                for (int j = 0; j < 3; ++j) {
                    gacc[i][j] += a0[i] * bb[j];
                    macc[i][j] += a1[i] * bb[j];
                }
#pragma unroll
            for (int j = 0; j < 4; ++j)
#pragma unroll
                for (int i = 0; i < 3; ++i)
                    cacc[j][i] += vv[j] * a0[i];
        }
        __syncthreads();
    }
    size_t pbase = (size_t)sp * (BSZ * NH) + b * NH + h;
    float* Gp = Gpart + pbase * 2304;
    float* Mp = Mpart + pbase * 2304;
    float* Cp = Cpart + pbase * 3072;
#pragma unroll
    for (int i = 0; i < 3; ++i)
#pragma unroll
        for (int j = 0; j < 3; ++j) {
            Gp[(tx * 3 + i) * 48 + (ty * 3 + j)] = gacc[i][j];
            Mp[(tx * 3 + i) * 48 + (ty * 3 + j)] = macc[i][j];
        }
#pragma unroll
    for (int j = 0; j < 4; ++j)
#pragma unroll
        for (int i = 0; i < 3; ++i)
            Cp[(ty * 4 + j) * 48 + (tx * 3 + i)] = cacc[j][i];
}

// reduce GSPLIT partials into the per-k slot of Gb/Mb/Cb
__global__ __launch_bounds__(256) void gram_reduce(const float* __restrict__ Gpart,
                                                   const float* __restrict__ Mpart,
                                                   const float* __restrict__ Cpart,
                                                   float* __restrict__ Gb,
                                                   float* __restrict__ Mb,
                                                   float* __restrict__ Cb,
                                                   int k)
{
    int p = blockIdx.x;               // b*NH+h
    size_t ob = ((size_t)k * (BSZ * NH) + p);
    for (int idx = threadIdx.x; idx < 2304; idx += 256) {
        float sg = 0.f, sm = 0.f;
#pragma unroll
        for (int sp = 0; sp < GSPLIT; ++sp) {
            size_t pb = ((size_t)sp * (BSZ * NH) + p);
            sg += Gpart[pb * 2304 + idx];
            sm += Mpart[pb * 2304 + idx];
        }
        Gb[ob * 2304 + idx] = sg;
        Mb[ob * 2304 + idx] = sm;
    }
    for (int idx = threadIdx.x; idx < 3072; idx += 256) {
        float sc = 0.f;
#pragma unroll
        for (int sp = 0; sp < GSPLIT; ++sp)
            sc += Cpart[((size_t)sp * (BSZ * NH) + p) * 3072 + idx];
        Cb[ob * 3072 + idx] = sc;
    }
}

// ---------------- per-(k,b,h) fused solver: F = C_v * (scl^2 * P*P*H) ----------------
// H = (G+ridge I)^{-1} via Gauss-Jordan (1 barrier/pivot, triangular ranges);
// P = H*M; R = H*M^T; Q = R*P; Q2 = Q*Q; sigma^4 = lambda_max(Q2) (48 iters);
// X = P*H; W^T = s2*(P*X)^T into Pt (dead); Cv into Mm/A (dead); F = Cv*W -> Fb.
__global__ __launch_bounds__(256) void solver_kernel(const float* __restrict__ Gb,
                                                     const float* __restrict__ Mb,
                                                     const float* __restrict__ Cb,
                                                     float* __restrict__ Fb,
                                                     const float* __restrict__ log_ridges,
                                                     const float* __restrict__ log_gammas)
{
    int blk = blockIdx.x;                 // (k*BSZ + b)*NH + h
    int k = blk / (BSZ * NH);
    int tid = threadIdx.x;
    int ti = tid >> 4, tj = tid & 15;
    int i0 = ti * 3, j0 = tj * 3;

    __shared__ float A [48 * SST];        // G -> GJ(D) -> M^T -> R -> Q^T -> X^T -> Cv[48:64]
    __shared__ float Hs[48 * SST];        // I -> B -> H = G^{-1}
    __shared__ float Mm[48 * SST];        // M -> Q -> Cv[0:48]
    __shared__ float Pm[48 * SST];        // P  (row-major)
    __shared__ float Pt[48 * SST];        // P^T -> Q2 -> W^T (scaled)
    __shared__ float pvb[4][SST];

    size_t base = (size_t)blk;
    const float* Gp = Gb + base * 2304;
    const float* Mp = Mb + base * 2304;
    const float* Cp = Cb + base * 3072;
    float ridge = expf(log_ridges[k]);

    for (int idx = tid; idx < 2304; idx += 256) {
        int i = idx / 48, j = idx % 48;
        A [i * SST + j] = Gp[idx] + ((i == j) ? ridge : 0.f);
        Hs[i * SST + j] = (i == j) ? 1.f : 0.f;
        Mm[i * SST + j] = Mp[idx];
    }
    __syncthreads();

    // ---- Gauss-Jordan, deferred row-scaling, 1 barrier/pivot, triangular ranges ----
    for (int p = 0; p < 48; ++p) {
        int p4 = p >> 2;
        float pr = 1.0f / fmaxf(A[p * SST + p], 1e-30f);   // SPD -> pivot > 0
        int c4a = p4 + 1;              // first full A float4 col-block (> p)
        int nA4 = 11 - p4;             // A blocks [c4a..11]
        int nb  = 3 - (p & 3);         // boundary scalar cols (p+1 .. 4*c4a-1)
        for (int q = tid; q < 576; q += 256) {   // 48 rows x 12 float4 blocks
            int i = q / 12, c = q % 12;
            if (i == p) continue;
            float f = A[i * SST + p] * pr;
            if (c < nA4) {
                int c4 = c4a + c;
                float4 prw = *(const float4*)&A[p * SST + c4 * 4];
                float4* d = (float4*)&A[i * SST + c4 * 4];
                float4 v = *d;
                v.x -= f * prw.x; v.y -= f * prw.y;
                v.z -= f * prw.z; v.w -= f * prw.w;
                *d = v;
            } else {
                int c4 = c - nA4;      // 0 .. p4  (Hs cols <= p; extras are f*0)
                float4 prw = *(const float4*)&Hs[p * SST + c4 * 4];
                float4* d = (float4*)&Hs[i * SST + c4 * 4];
                float4 v = *d;
                v.x -= f * prw.x; v.y -= f * prw.y;
                v.z -= f * prw.z; v.w -= f * prw.w;
                *d = v;
            }
        }
        if (nb) {
            for (int i = tid; i < 48; i += 256) {
                if (i == p) continue;
                float f = A[i * SST + p] * pr;
                for (int c = p + 1; c < 4 * c4a; ++c)
                    A[i * SST + c] -= f * A[p * SST + c];
            }
        }
        __syncthreads();
    }
    // H = D^{-1} B  (row-wise scale by 1/d_i, d_i = A[i][i])
    for (int idx = tid; idx < 2304; idx += 256) {
        int i = idx / 48, j = idx % 48;
        Hs[i * SST + j] /= fmaxf(A[i * SST + i], 1e-30f);
    }
    __syncthreads();
    // ---- M^T into A (GJ remnants dead) ----
    for (int idx = tid; idx < 2304; idx += 256) {
        int i = idx / 48, j = idx % 48;
        A[j * SST + i] = Mm[i * SST + j];
    }
    __syncthreads();
    // ---- P = H*M: tile = dot(Hs rows, Mt=A rows); store Pm and Pt ----
    {
        float acc[3][3];
        mm48_3x3(Hs, A, i0, j0, acc);
#pragma unroll
        for (int r = 0; r < 3; ++r)
#pragma unroll
            for (int c = 0; c < 3; ++c) {
                Pm[(i0 + r) * SST + j0 + c] = acc[r][c];
                Pt[(j0 + c) * SST + i0 + r] = acc[r][c];
            }
    }
    __syncthreads();
    // ---- R = H*M^T into A (Mt dead): dot(Hs rows, Mm rows) ----
    {
        float acc[3][3];
        mm48_3x3(Hs, Mm, i0, j0, acc);
        __syncthreads();                      // Mt reads done before overwriting A
#pragma unroll
        for (int r = 0; r < 3; ++r)
#pragma unroll
            for (int c = 0; c < 3; ++c)
                A[(i0 + r) * SST + j0 + c] = acc[r][c];
    }
    __syncthreads();
    // ---- Q = R*P: dot(A rows, Pt rows) -> Q into Mm (M dead), Q^T into A ----
    {
        float acc[3][3];
        mm48_3x3(A, Pt, i0, j0, acc);
        __syncthreads();                      // R/Pt reads done before overwrite
#pragma unroll
        for (int r = 0; r < 3; ++r)
#pragma unroll
            for (int c = 0; c < 3; ++c) {
                Mm[(i0 + r) * SST + j0 + c] = acc[r][c];
                A [(j0 + c) * SST + i0 + r] = acc[r][c];
            }
    }
    __syncthreads();
    // ---- Q2 = Q*Q: Q2[i][j] = dot(Q[i], Qt[j]) = dot(Mm[i], A[j]) -> into Pt (dead) ----
    {
        float acc[3][3];
        mm48_3x3(Mm, A, i0, j0, acc);
#pragma unroll
        for (int r = 0; r < 3; ++r)
#pragma unroll
            for (int c = 0; c < 3; ++c)
                Pt[(i0 + r) * SST + j0 + c] = acc[r][c];
    }
    __syncthreads();

    // ---- power iteration on Q2 (48 iters == 96 on Q): redundant per wave ----
    int ln = tid & 63, w = tid >> 6;
    float* pv = pvb[w];
    if (ln < 48) pv[ln] = ((float)((ln * 2654435761u) & 0xFFFF)) / 65536.0f + 0.5f;
    WB();
    float lam = 0.f;
    for (int it = 0; it < 49; ++it) {
        float z = 0.f;
        if (ln < 48) z = dot48(&Pt[ln * SST], pv);
        if (it == 48) {
            float nn = z * z;
            for (int off = 1; off < 64; off <<= 1) nn += __shfl_xor(nn, off);
            lam = sqrtf(nn);               // lambda_max(Q2) = sigma_max^4
            break;
        }
        if ((it & 3) == 3) {
            float nn = z * z;
            for (int off = 1; off < 64; off <<= 1) nn += __shfl_xor(nn, off);
            z *= rsqrtf(fmaxf(nn, 1e-30f));
        }
        WB();
        if (ln < 48) pv[ln] = z;
        WB();
    }
    float sigma = sqrtf(sqrtf(fmaxf(lam, 0.f)));
    float gamma = expf(log_gammas[k]);
    float scl = fminf(gamma, 1.f) / fmaxf(fmaxf(sigma, 1e-8f), 1.f);
    float s2 = scl * scl;

    // ---- X^T into A (Qt dead; waves write only after their own power loop;
    //      all waves' Q2-phase A reads are behind the pre-power barrier) ----
    {
        float acc[3][3];
        mm48_3x3(Pm, Hs, i0, j0, acc);
        __syncthreads();                      // ALL waves done with power (Pt) + Q2 reads
#pragma unroll
        for (int r = 0; r < 3; ++r)
#pragma unroll
            for (int c = 0; c < 3; ++c)
                A[(j0 + c) * SST + i0 + r] = acc[r][c];
    }
    __syncthreads();
    // ---- W^T = s2*(P*X)^T into Pt (Q2 dead after power) ----
    {
        float acc[3][3];
        mm48_3x3(Pm, A, i0, j0, acc);
        __syncthreads();                      // power-phase Pt reads done (barrier above covers); A reads done
#pragma unroll
        for (int r = 0; r < 3; ++r)
#pragma unroll
            for (int c = 0; c < 3; ++c)
                Pt[(j0 + c) * SST + i0 + r] = s2 * acc[r][c];
    }
    __syncthreads();
    // ---- Cv into Mm (rows 0..47) and A (rows 48..63); Mm/A dead ----
    for (int idx = tid; idx < 3072; idx += 256) {
        int row = idx / 48, col = idx % 48;
        float v = Cp[idx];
        if (row < 48) Mm[row * SST + col] = v;
        else          A [(row - 48) * SST + col] = v;
    }
    __syncthreads();
    // ---- F = Cv * W: F[d][j] = dot(Cv[d], Wt=Pt[j]); 4x3 reg tile; i0 never crosses 48 ----
    {
        int fi0 = ti * 4, fj0 = tj * 3;
        const float* crow0 = (fi0 < 48) ? &Mm[fi0 * SST] : &A[(fi0 - 48) * SST];
        float acc[4][3];
#pragma unroll
        for (int r = 0; r < 4; ++r)
#pragma unroll
            for (int c = 0; c < 3; ++c) acc[r][c] = 0.f;
#pragma unroll 4
        for (int m = 0; m < 12; ++m) {
            float4 a0 = *(const float4*)(crow0 + 0 * SST + m * 4);
            float4 a1 = *(const float4*)(crow0 + 1 * SST + m * 4);
            float4 a2 = *(const float4*)(crow0 + 2 * SST + m * 4);
            float4 a3 = *(const float4*)(crow0 + 3 * SST + m * 4);
            float4 b0 = *(const float4*)(&Pt[(fj0 + 0) * SST] + m * 4);
            float4 b1 = *(const float4*)(&Pt[(fj0 + 1) * SST] + m * 4);
            float4 b2 = *(const float4*)(&Pt[(fj0 + 2) * SST] + m * 4);
            acc[0][0] += a0.x*b0.x + a0.y*b0.y + a0.z*b0.z + a0.w*b0.w;
            acc[0][1] += a0.x*b1.x + a0.y*b1.y + a0.z*b1.z + a0.w*b1.w;
            acc[0][2] += a0.x*b2.x + a0.y*b2.y + a0.z*b2.z + a0.w*b2.w;
            acc[1][0] += a1.x*b0.x + a1.y*b0.y + a1.z*b0.z + a1.w*b0.w;
            acc[1][1] += a1.x*b1.x + a1.y*b1.y + a1.z*b1.z + a1.w*b1.w;
            acc[1][2] += a1.x*b2.x + a1.y*b2.y + a1.z*b2.z + a1.w*b2.w;
            acc[2][0] += a2.x*b0.x + a2.y*b0.y + a2.z*b0.z + a2.w*b0.w;
            acc[2][1] += a2.x*b1.x + a2.y*b1.y + a2.z*b1.z + a2.w*b1.w;
            acc[2][2] += a2.x*b2.x + a2.y*b2.y + a2.z*b2.z + a2.w*b2.w;
            acc[3][0] += a3.x*b0.x + a3.y*b0.y + a3.z*b0.z + a3.w*b0.w;
            acc[3][1] += a3.x*b1.x + a3.y*b1.y + a3.z*b1.z + a3.w*b1.w;
            acc[3][2] += a3.x*b2.x + a3.y*b2.y + a3.z*b2.z + a3.w*b2.w;
        }
#pragma unroll
        for (int r = 0; r < 4; ++r)
#pragma unroll
            for (int c = 0; c < 3; ++c)
                Fb[base * 3072 + (size_t)(fi0 + r) * 48 + fj0 + c] = acc[r][c];
    }
}

// ---------------- W_cmb build -> bf16 hi/lo ----------------
__global__ __launch_bounds__(256) void wcmb_kernel(const float* __restrict__ WQ,
                                                   const float* __restrict__ Fb,
                                                   const float* __restrict__ gate_alphas,
                                                   u16* __restrict__ Wh,
                                                   u16* __restrict__ Wl)
{
    int dt = blockIdx.x;  // row tile (0..15)
    int h = blockIdx.y, b = blockIdx.z;
    __shared__ float wq[64][49];
    __shared__ float fs[64][49];
    int tid = threadIdx.x;
    int tx = tid & 15, ty = tid >> 4;
    float acc[4][4] = {};
    for (int k = 0; k < NKOPS; ++k) {
        float gate = 1.0f / (1.0f + expf(-gate_alphas[k]));
        for (int idx = tid; idx < 64 * 48; idx += 256) {
            int rr = idx / 48, cc = idx % 48;
            wq[rr][cc] = WQ[((size_t)k * DDIM + dt * 64 + rr) * HR + h * RDIM + cc];
            fs[rr][cc] = gate * Fb[(((size_t)k * BSZ + b) * NH + h) * 3072 + idx];
        }
        __syncthreads();
        for (int r = 0; r < 48; ++r) {
            float a[4], bb[4];
#pragma unroll
            for (int i = 0; i < 4; ++i) { a[i] = wq[tx * 4 + i][r]; bb[i] = fs[ty * 4 + i][r]; }
#pragma unroll
            for (int i = 0; i < 4; ++i)
#pragma unroll
                for (int j = 0; j < 4; ++j)
                    acc[i][j] += a[i] * bb[j];
        }
        __syncthreads();
    }
#pragma unroll
    for (int i = 0; i < 4; ++i)
#pragma unroll
        for (int j = 0; j < 4; ++j) {
            size_t o = ((size_t)b * DDIM + dt * 64 + tx * 4 + i) * HHD + h * HDIM + ty * 4 + j;
            float v = acc[i][j];
            u16 hh = f2bf(v);
            Wh[o] = hh;
            Wl[o] = f2bf(v - bf2f(hh));
        }
}

// ---------------- host launch ----------------
extern "C" void kernel_launch(void* const* d_in, const int* in_sizes, int n_in,
                              void* d_out, int out_size, void* d_ws, size_t ws_size,
                              hipStream_t stream)
{
    const float* hs          = (const float*)d_in[0];
    const float* WK          = (const float*)d_in[1];
    const float* WQ          = (const float*)d_in[2];
    const float* WV          = (const float*)d_in[3];
    const float* WO          = (const float*)d_in[4];
    const float* ln_g        = (const float*)d_in[5];
    const float* ln_b        = (const float*)d_in[6];
    const float* gate_alphas = (const float*)d_in[7];
    const float* gate_alpha  = (const float*)d_in[8];
    const float* log_ridges  = (const float*)d_in[9];
    const float* log_gammas  = (const float*)d_in[10];
    const int*   pl_ptr      = (const int*)d_in[11];
    float* out = (float*)d_out;

    float* wsf = (float*)d_ws;
    u16* n_hi   = (u16*)(wsf + 0);          // 8,388,608 u16
    u16* n_lo   = (u16*)(wsf + 4194304);
    u16* WVt_h  = (u16*)(wsf + 8388608);    // 1,048,576 u16
    u16* WVt_l  = (u16*)(wsf + 8912896);
    u16* WKt_h  = (u16*)(wsf + 9437184);    // 786,432 u16
    u16* WKt_l  = (u16*)(wsf + 9830400);
    float* Vp   = wsf + 10223616;           // 8,388,608 f32
    float* Kp   = wsf + 18612224;           // 6,291,456 f32
    float* Gb   = wsf + 24903680;           // 589,824
    float* Mb   = wsf + 25493504;           // 589,824
    float* Cb   = wsf + 26083328;           // 786,432  (end: 26,869,760 f = 102.5 MiB)
    // aliases (lifetimes disjoint, stream-ordered)
    u16* Wcmb_h  = (u16*)Vp;                // after grams
    u16* Wcmb_l  = (u16*)(Vp + 2097152);
    u16* Wfint_h = (u16*)(Vp + 4194304);
    u16* Wfint_l = (u16*)(Vp + 6291456);
    u16* WOt_h   = (u16*)Kp;                // after grams
    u16* WOt_l   = (u16*)(Kp + 524288);
    float* Fb    = Kp + 1048576;            // 786,432
    // gram partials live in d_out (dead before final GEMM overwrites all of d_out)
    float* Gpart = out;                     // 16*64*2304 = 2,359,296
    float* Mpart = out + 2359296;           // 2,359,296
    float* Cpart = out + 4718592;           // 16*64*3072 = 3,145,728 (end 7,864,320 < 8,388,608)

    ln_kernel<<<BSZ * TLEN, 256, 0, stream>>>(hs, ln_g, ln_b, n_hi, n_lo);

    // WVt = WV^T (hi/lo);  Vp = normed_prefix @ WV
    transcvt<<<dim3(HHD / 32, DDIM / 32), 256, 0, stream>>>(WV, WVt_h, WVt_l, DDIM, HHD);
    gemm_mfma<0><<<dim3(HHD / 128, TLEN / 128, BSZ), 256, 0, stream>>>(
        n_hi, n_lo, (long)TLEN * DDIM, WVt_h, WVt_l, 0,
        Vp, nullptr, nullptr, (long)TLEN * HHD,
        TLEN, HHD, DDIM, pl_ptr, nullptr);

    for (int k = 0; k < NKOPS; ++k) {
        transcvt<<<dim3(HR / 32, DDIM / 32), 256, 0, stream>>>(
            WK + (size_t)k * DDIM * HR, WKt_h, WKt_l, DDIM, HR);
        gemm_mfma<0><<<dim3(HR / 128, TLEN / 128, BSZ), 256, 0, stream>>>(
            n_hi, n_lo, (long)TLEN * DDIM, WKt_h, WKt_l, 0,
            Kp, nullptr, nullptr, (long)TLEN * HR,
            TLEN, HR, DDIM, pl_ptr, nullptr);
        gram_kernel<<<dim3(NH, BSZ, GSPLIT), 256, 0, stream>>>(Kp, Vp, Gpart, Mpart, Cpart, pl_ptr);
        gram_reduce<<<BSZ * NH, 256, 0, stream>>>(Gpart, Mpart, Cpart, Gb, Mb, Cb, k);
    }

    // WOt = WO^T (into Kp region, now dead)
    transcvt<<<dim3(DDIM / 32, HHD / 32), 256, 0, stream>>>(WO, WOt_h, WOt_l, HHD, DDIM);

    solver_kernel<<<NKOPS * BSZ * NH, 256, 0, stream>>>(Gb, Mb, Cb, Fb, log_ridges, log_gammas);

    wcmb_kernel<<<dim3(DDIM / 64, NH, BSZ), 256, 0, stream>>>(WQ, Fb, gate_alphas, Wcmb_h, Wcmb_l);

    // Wfint[b] = WO^T @ Wcmb[b]^T  == Wfin[b]^T, written bf16 hi/lo row-major
    gemm_mfma<1><<<dim3(DDIM / 128, DDIM / 128, BSZ), 256, 0, stream>>>(
        WOt_h, WOt_l, 0, Wcmb_h, Wcmb_l, (long)DDIM * HHD,
        nullptr, Wfint_h, Wfint_l, (long)DDIM * DDIM,
        DDIM, DDIM, HHD, nullptr, nullptr);

    // out[b] = sigmoid(gate_alpha) * normed[b] @ Wfin[b]
    gemm_mfma<0><<<dim3(DDIM / 128, TLEN / 128, BSZ), 256, 0, stream>>>(
        n_hi, n_lo, (long)TLEN * DDIM, Wfint_h, Wfint_l, (long)DDIM * DDIM,
        out, nullptr, nullptr, (long)TLEN * DDIM,
        TLEN, DDIM, DDIM, nullptr, gate_alpha);
}